// Round 5
// baseline (1007.910 us; speedup 1.0000x reference)
//
#include <hip/hip_runtime.h>
#include <math.h>

#define BB 256
#define NEL 90
#define NMAX 270
#define C1 448
#define C2 256
#define PIN 448
#define LATH 128
#define SGE 64
#define P1 512
#define EPSB 1e-5f

#define XROWCAP 44032           /* row capacity of x/xwT buffers (total32 ~38.6k fixed-seed) */
#define GJT (XROWCAP / 128)     /* 344 GEMM j-tiles */

typedef short shortx8 __attribute__((ext_vector_type(8)));
typedef float floatx4 __attribute__((ext_vector_type(4)));

__device__ __forceinline__ float bf2f(unsigned short u) {
  return __uint_as_float(((unsigned)u) << 16);
}
__device__ __forceinline__ unsigned short f2bf(float f) {
  unsigned x = __float_as_uint(f);
  unsigned r = (x + 0x7fffu + ((x >> 16) & 1u)) >> 16;
  return (unsigned short)r;
}
// async 16B global->LDS (gfx950). LDS dest: wave-uniform base + lane*16.
__device__ __forceinline__ void gld16(const void* g, void* l) {
  __builtin_amdgcn_global_load_lds(
      (const __attribute__((address_space(1))) unsigned int*)g,
      (__attribute__((address_space(3))) unsigned int*)l, 16, 0, 0);
}

// ================= mega prologue: prep | scan | physpe | wprep x2 | fold x2 | pad
#define NB_PREP  BB
#define NB_SCAN  1
#define NB_PHYS  NEL
#define NB_WP1   (14 * 42)
#define NB_WP2   (14 * 24)
#define NB_FOLD  112
#define NB_PAD   64
#define SETUP_GRID (NB_PREP + NB_SCAN + NB_PHYS + NB_WP1 + NB_WP2 + 2 * NB_FOLD + NB_PAD)

__global__ __launch_bounds__(256) void k_setup(
    const int* __restrict__ comp, const int* __restrict__ sg, const float* __restrict__ lat,
    const float* __restrict__ sg_emb,
    const float* __restrict__ lW1, const float* __restrict__ lb1,
    const float* __restrict__ lg1, const float* __restrict__ lbe1,
    const float* __restrict__ lm1, const float* __restrict__ lv1,
    const float* __restrict__ lW2, const float* __restrict__ lb2,
    const float* __restrict__ lg2, const float* __restrict__ lbe2,
    const float* __restrict__ lm2, const float* __restrict__ lv2,
    const int* __restrict__ period_idx, const int* __restrict__ group_idx,
    const float* __restrict__ z_emb, const float* __restrict__ period_t,
    const float* __restrict__ group_t, const float* __restrict__ props,
    const float* __restrict__ Wp, const float* __restrict__ bp,
    const float* __restrict__ Wphys, const float* __restrict__ bphys,
    const float* __restrict__ gat1_W, const float* __restrict__ gat1_as,
    const float* __restrict__ gat1_ad, const float* __restrict__ gat1_b,
    const float* __restrict__ gat2_W, const float* __restrict__ gat2_as,
    const float* __restrict__ gat2_ad, const float* __restrict__ gat2_b,
    float* __restrict__ sgx, float* __restrict__ latx, int* __restrict__ z,
    int* __restrict__ natoms, int* __restrict__ off, int* __restrict__ aoff,
    int* __restrict__ meta,
    float* __restrict__ zerobuf, float* __restrict__ physpe,
    unsigned short* __restrict__ wt1, unsigned short* __restrict__ wt2,
    float* __restrict__ wsv1, float* __restrict__ wdv1,
    float* __restrict__ wsv2, float* __restrict__ wdv2, float* __restrict__ pad2) {
  int r = blockIdx.x;
  int tid = threadIdx.x;
  int wv = tid >> 6, lane = tid & 63;

  if (r < NB_PREP) {  // ---- prep (z, sgx, latx) ----
    int b = r;
    __shared__ int cum[NEL];
    __shared__ float hbuf[LATH];
    __shared__ float latl[6];
    if (tid == 0) {
      int s = 0;
      for (int e = 0; e < NEL; ++e) { s += comp[b * NEL + e]; cum[e] = s; }
    }
    if (tid < 6) latl[tid] = lat[b * 6 + tid];
    __syncthreads();
    int n = cum[NEL - 1];
    for (int t = tid; t < NMAX; t += 256) {
      int zz = -1;
      if (t < n) {
        for (int e = 0; e < NEL; ++e) { if (cum[e] > t) { zz = e; break; } }
      }
      z[b * NMAX + t] = zz;
    }
    if (tid < SGE) sgx[b * SGE + tid] = sg_emb[sg[b] * SGE + tid];
    if (tid < LATH) {
      float acc = lb1[tid];
      for (int k = 0; k < 6; ++k) acc += latl[k] * lW1[k * LATH + tid];
      acc = (acc - lm1[tid]) * lg1[tid] * rsqrtf(lv1[tid] + EPSB) + lbe1[tid];
      hbuf[tid] = acc;
    }
    __syncthreads();
    if (tid < LATH) {
      float acc = lb2[tid];
      for (int k = 0; k < LATH; ++k) acc += hbuf[k] * lW2[k * LATH + tid];
      acc = (acc - lm2[tid]) * lg2[tid] * rsqrtf(lv2[tid] + EPSB) + lbe2[tid];
      latx[b * LATH + tid] = acc;
    }
    return;
  }
  r -= NB_PREP;
  if (r < NB_SCAN) {  // ---- scans (natoms, off32 kext-padded, aoff) + zero page
    __shared__ int sh[BB];
    zerobuf[tid] = 0.f;
    int v0 = 0;
    for (int e = 0; e < NEL; ++e) v0 += comp[tid * NEL + e];
    natoms[tid] = v0;
    int kx = ((v0 + 31) >> 5) << 5;   // kext-aligned row window per graph
    sh[tid] = kx;
    for (int d = 1; d < BB; d <<= 1) {
      __syncthreads();
      int v = (tid >= d) ? sh[tid - d] : 0;
      __syncthreads();
      sh[tid] += v;
    }
    __syncthreads();
    off[tid] = sh[tid] - kx;
    if (tid == BB - 1) meta[0] = sh[tid];   // total32 = padded row count
    __syncthreads();
    int sz = 3 * ((((v0 + 15) >> 4) << 4)) * ((((v0 + 31) >> 5) << 5));
    sh[tid] = sz;
    for (int d = 1; d < BB; d <<= 1) {
      __syncthreads();
      int v = (tid >= d) ? sh[tid - d] : 0;
      __syncthreads();
      sh[tid] += v;
    }
    __syncthreads();
    aoff[tid] = sh[tid] - sz;
    return;
  }
  r -= NB_SCAN;
  if (r < NB_PHYS) {  // ---- physpe rows ----
    int e = r;
    __shared__ float ph[128];
    if (tid < 32) ph[tid] = z_emb[e * 32 + tid];
    else if (tid < 64) ph[tid] = period_t[period_idx[e] * 32 + tid - 32];
    else if (tid < 96) ph[tid] = group_t[group_idx[e] * 32 + tid - 64];
    else if (tid < 128) {
      int j = tid - 96;
      float acc = bp[j];
      for (int k = 0; k < 20; ++k) acc += props[e * 20 + k] * Wp[k * 32 + j];
      ph[tid] = acc;
    }
    __syncthreads();
    float acc = bphys[tid];
    for (int k = 0; k < 128; ++k) acc += ph[k] * Wphys[k * 256 + tid];
    physpe[e * 256 + tid] = acc;
    return;
  }
  r -= NB_PHYS;
  if (r < NB_WP1 + NB_WP2) {  // ---- W transpose to bf16 W^T ----
    const float* W;
    unsigned short* Wt;
    int NC3, bx, by;
    if (r < NB_WP1) { W = gat1_W; Wt = wt1; NC3 = 3 * C1; bx = r % 14; by = r / 14; }
    else { int r2 = r - NB_WP1; W = gat2_W; Wt = wt2; NC3 = 3 * C2; bx = r2 % 14; by = r2 / 14; }
    int k0 = bx << 5, c0 = by << 5;
    __shared__ float ts[32][33];
    int e4 = tid << 2;
    int kk = e4 >> 5, cc = e4 & 31;
    float4 v = *(const float4*)(W + (size_t)(k0 + kk) * NC3 + c0 + cc);
    ts[kk][cc] = v.x; ts[kk][cc + 1] = v.y; ts[kk][cc + 2] = v.z; ts[kk][cc + 3] = v.w;
    __syncthreads();
    int c2 = tid & 31, kg = tid >> 5;
    ushort4 u;
    u.x = f2bf(ts[kg * 4 + 0][c2]); u.y = f2bf(ts[kg * 4 + 1][c2]);
    u.z = f2bf(ts[kg * 4 + 2][c2]); u.w = f2bf(ts[kg * 4 + 3][c2]);
    *(ushort4*)(Wt + (size_t)(c0 + c2) * 448 + k0 + (kg << 2)) = u;
    return;
  }
  r -= NB_WP1 + NB_WP2;
  if (r < 2 * NB_FOLD) {  // ---- fold a_s/a_d through W ----
    const float* W; const float* as_; const float* ad_;
    float* wsv; float* wdv; int NC3, C, kb;
    if (r < NB_FOLD) { W = gat1_W; as_ = gat1_as; ad_ = gat1_ad; wsv = wsv1; wdv = wdv1; NC3 = 3 * C1; C = C1; kb = r << 2; }
    else { int r2 = r - NB_FOLD; W = gat2_W; as_ = gat2_as; ad_ = gat2_ad; wsv = wsv2; wdv = wdv2; NC3 = 3 * C2; C = C2; kb = r2 << 2; }
    int k = kb + wv;
    for (int h = 0; h < 3; ++h) {
      float ss = 0.f, sd = 0.f;
      for (int c = lane; c < C; c += 64) {
        float wvv = W[(size_t)k * NC3 + h * C + c];
        ss += wvv * as_[h * C + c];
        sd += wvv * ad_[h * C + c];
      }
      for (int o = 32; o > 0; o >>= 1) { ss += __shfl_xor(ss, o); sd += __shfl_xor(sd, o); }
      if (lane == 0) { wsv[k * 3 + h] = ss; wdv[k * 3 + h] = sd; }
    }
    return;
  }
  r -= 2 * NB_FOLD;
  {  // ---- pad-row value after layer 2 ----
    int c = (r << 2) + wv;
    float s = 0.f;
    for (int k = lane; k < C1; k += 64) {
      const float* wr = gat2_W + (size_t)k * (3 * C2) + c;
      s += gat1_b[k] * (wr[0] + wr[C2] + wr[2 * C2]);
    }
    for (int o = 32; o > 0; o >>= 1) s += __shfl_xor(s, o);
    if (lane == 0) pad2[c] = s * (1.f / 3.f) + gat2_b[c];
  }
}

// ---------------- packed node features x0 [total32,448] bf16 + zero pads ---
__global__ __launch_bounds__(256) void k_nodep(
    const int* __restrict__ z, const int* __restrict__ off, const int* __restrict__ natoms,
    const float* __restrict__ physpe, const float* __restrict__ latx,
    const float* __restrict__ sgx, unsigned short* __restrict__ x0) {
  int b = blockIdx.x;
  int n = natoms[b], ob = off[b];
  int tid = threadIdx.x;
  __shared__ int zl[NMAX];
  for (int t = tid; t < n; t += 256) zl[t] = z[b * NMAX + t];
  __syncthreads();
  int items = n * 56;
  for (int e = tid; e < items; e += 256) {
    int t = e / 56, c8 = (e - t * 56) << 3;
    int zt = zl[t];
    float v[8];
    if (c8 < 256) {
      float4 a = *(const float4*)(physpe + zt * 256 + c8);
      float4 c = *(const float4*)(physpe + zt * 256 + c8 + 4);
      v[0] = a.x; v[1] = a.y; v[2] = a.z; v[3] = a.w;
      v[4] = c.x; v[5] = c.y; v[6] = c.z; v[7] = c.w;
    } else if (c8 < 384) {
      float4 a = *(const float4*)(latx + b * LATH + c8 - 256);
      float4 c = *(const float4*)(latx + b * LATH + c8 - 252);
      v[0] = a.x; v[1] = a.y; v[2] = a.z; v[3] = a.w;
      v[4] = c.x; v[5] = c.y; v[6] = c.z; v[7] = c.w;
    } else {
      float4 a = *(const float4*)(sgx + b * SGE + c8 - 384);
      float4 c = *(const float4*)(sgx + b * SGE + c8 - 380);
      v[0] = a.x; v[1] = a.y; v[2] = a.z; v[3] = a.w;
      v[4] = c.x; v[5] = c.y; v[6] = c.z; v[7] = c.w;
    }
    unsigned short u[8];
    #pragma unroll
    for (int i = 0; i < 8; ++i) u[i] = f2bf(v[i]);
    *(uint4*)(x0 + (size_t)(ob + t) * PIN + c8) = *(uint4*)u;
  }
  // zero pad rows [n, kext) so GEMM's XW of pad rows is defined (NaN-safe)
  int kext = ((n + 31) >> 5) << 5;
  int pitems = (kext - n) * 56;
  for (int e = tid; e < pitems; e += 256) {
    int rr = e / 56, c8 = (e - rr * 56) << 3;
    uint4 z4; z4.x = z4.y = z4.z = z4.w = 0u;
    *(uint4*)(x0 + (size_t)(ob + n + rr) * PIN + c8) = z4;
  }
}

// ---------------- asrc/adst: one WAVE per row (coalesced) ----------------
__global__ __launch_bounds__(256) void k_av2(
    const unsigned short* __restrict__ x, const float* __restrict__ wsv,
    const float* __restrict__ wdv, const int* __restrict__ off,
    const int* __restrict__ natoms, float* __restrict__ asrc,
    float* __restrict__ adst, int K) {
  __shared__ float sw[C1 * 3], dw[C1 * 3];
  int tid = threadIdx.x;
  for (int e = tid; e < K * 3; e += 256) { sw[e] = wsv[e]; dw[e] = wdv[e]; }
  __syncthreads();
  int total = off[BB - 1] + natoms[BB - 1];
  int wv = tid >> 6, lane = tid & 63;
  int nk8 = K >> 3;
  int stride = gridDim.x << 2;
  for (int row = (blockIdx.x << 2) + wv; row < total; row += stride) {
    float s0 = 0.f, s1 = 0.f, s2 = 0.f, d0 = 0.f, d1 = 0.f, d2 = 0.f;
    if (lane < nk8) {
      uint4 raw = *(const uint4*)(x + (size_t)row * K + (lane << 3));
      unsigned short us[8];
      *(uint4*)us = raw;
      #pragma unroll
      for (int u = 0; u < 8; ++u) {
        float xv = bf2f(us[u]);
        int kb = ((lane << 3) + u) * 3;
        s0 += xv * sw[kb + 0]; s1 += xv * sw[kb + 1]; s2 += xv * sw[kb + 2];
        d0 += xv * dw[kb + 0]; d1 += xv * dw[kb + 1]; d2 += xv * dw[kb + 2];
      }
    }
    #pragma unroll
    for (int o = 32; o > 0; o >>= 1) {
      s0 += __shfl_xor(s0, o); s1 += __shfl_xor(s1, o); s2 += __shfl_xor(s2, o);
      d0 += __shfl_xor(d0, o); d1 += __shfl_xor(d1, o); d2 += __shfl_xor(d2, o);
    }
    if (lane == 0) {
      asrc[row * 3 + 0] = s0; asrc[row * 3 + 1] = s1; asrc[row * 3 + 2] = s2;
      adst[row * 3 + 0] = d0; adst[row * 3 + 1] = d1; adst[row * 3 + 2] = d2;
    }
  }
}

// ---------------- alpha materialization (sharded): one (b,h,mtile)/block ---
#define MTMAX 17
__global__ __launch_bounds__(256) void k_alpha(
    const float* __restrict__ asrc, const float* __restrict__ adst,
    const int* __restrict__ off, const int* __restrict__ natoms,
    const int* __restrict__ aoff, unsigned short* __restrict__ alpha) {
  int bid = blockIdx.x;
  int b = bid & (BB - 1);
  int hm = bid >> 8;
  int h = hm % 3;
  int mt = hm / 3;
  int n = natoms[b];
  if (n == 0) return;
  int mtn = (n + 15) >> 4;
  if (mt >= mtn) return;
  int ktn = (n + 31) >> 5;
  int rext = mtn << 4, kext = ktn << 5;
  int ob = off[b];
  size_t ab = (size_t)aoff[b] + (size_t)h * rext * kext;
  int tid = threadIdx.x;
  int wv = tid >> 6, lane = tid & 63;
  __shared__ float asl[288];
  for (int j = tid; j < kext; j += 256)
    asl[j] = (j < n) ? asrc[(ob + j) * 3 + h] : 0.f;
  __syncthreads();
  #pragma unroll
  for (int r = 0; r < 4; ++r) {
    int i = (mt << 4) + (wv << 2) + r;
    unsigned short* rowp = alpha + ab + (size_t)i * kext;
    if (i >= n) {
      for (int j = lane; j < kext; j += 64) rowp[j] = 0;
      continue;
    }
    float ad = adst[(ob + i) * 3 + h];
    float m = -1e30f;
    for (int j = lane; j < n; j += 64) {
      float sc = asl[j] + ad;
      sc = fmaxf(sc, 0.2f * sc);
      m = fmaxf(m, sc);
    }
    for (int o = 32; o > 0; o >>= 1) m = fmaxf(m, __shfl_xor(m, o));
    float s = 0.f;
    for (int j = lane; j < n; j += 64) {
      float sc = asl[j] + ad;
      sc = fmaxf(sc, 0.2f * sc);
      s += __expf(sc - m);
    }
    for (int o = 32; o > 0; o >>= 1) s += __shfl_xor(s, o);
    float rs = 1.f / s;
    for (int j = lane; j < kext; j += 64) {
      float v = 0.f;
      if (j < n) {
        float sc = asl[j] + ad;
        sc = fmaxf(sc, 0.2f * sc);
        v = __expf(sc - m) * rs;
      }
      rowp[j] = f2bf(v);
    }
  }
}

// ---------------- chunked dense GEMM: xwT rows = chunk cols, transposed ----
// Chunk covers ncb cblks (64 cols each) x 3 heads -> 3*ncb N-tiles.
// xwT chunk layout: [(h*ncb + i)*64 + local_c][total] bf16, pitch = total32.
// BM=128 BN=64 BK=32, gld16 dbuf, XOR-swizzled chunks (both-sides involution).
__global__ __launch_bounds__(256, 4) void k_gemm(
    const unsigned short* __restrict__ X, const unsigned short* __restrict__ W,
    const int* __restrict__ meta, const float* __restrict__ zerobuf,
    unsigned short* __restrict__ xwT, int C, int cb0, int ncb) {
  int total = meta[0];
  int NBT = 3 * ncb;
  int mb = blockIdx.x / NBT;
  int m0 = mb << 7;
  if (m0 >= total) return;
  int nb = blockIdx.x - mb * NBT;
  int h = nb / ncb;
  int i = nb - h * ncb;
  int colbase = h * C + ((cb0 + i) << 6);   // row base in Wt
  int bandbase = nb << 6;                    // row base in xwT chunk
  int tid = threadIdx.x;
  int wv = tid >> 6, lane = tid & 63;
  int m16 = lane & 15, q = lane >> 4;

  __shared__ unsigned short As[2][128 * 32];  // 8 KB each
  __shared__ unsigned short Bs[2][64 * 32];   // 4 KB each

  int l4 = lane >> 2, ci = lane & 3;
  int ra0 = (wv << 4) + l4;
  int ra1 = ra0 + 64;
  int rb  = (wv << 4) + l4;
  // pre-swizzled global sources (LDS dest linear; read applies same XOR)
  const unsigned short* asrc0 = (m0 + ra0 < total)
      ? (X + (size_t)(m0 + ra0) * 448 + ((ci ^ (ra0 & 3)) << 3))
      : (const unsigned short*)zerobuf;
  const unsigned short* asrc1 = (m0 + ra1 < total)
      ? (X + (size_t)(m0 + ra1) * 448 + ((ci ^ (ra1 & 3)) << 3))
      : (const unsigned short*)zerobuf;
  const unsigned short* bsrc = W + (size_t)(colbase + rb) * 448 + ((ci ^ (rb & 3)) << 3);

  floatx4 acc[2][4];
  #pragma unroll
  for (int ti = 0; ti < 2; ++ti)
    #pragma unroll
    for (int nt = 0; nt < 4; ++nt) acc[ti][nt] = (floatx4)0.f;

  gld16(asrc0, &As[0][wv << 9]);
  gld16(asrc1, &As[0][2048 + (wv << 9)]);
  gld16(bsrc, &Bs[0][wv << 9]);
  __syncthreads();

  #pragma unroll 2
  for (int s = 0; s < 14; ++s) {
    int cur = s & 1;
    if (s < 13) {
      int k1 = (s + 1) << 5;
      int nxt = cur ^ 1;
      gld16(asrc0 + k1, &As[nxt][wv << 9]);
      gld16(asrc1 + k1, &As[nxt][2048 + (wv << 9)]);
      gld16(bsrc + k1, &Bs[nxt][wv << 9]);
    }
    const unsigned short* Ab = As[cur];
    const unsigned short* Bb = Bs[cur];
    shortx8 bfr[4];
    #pragma unroll
    for (int nt = 0; nt < 4; ++nt) {
      int rr = (nt << 4) + m16;
      bfr[nt] = *(const shortx8*)(Bb + rr * 32 + ((q ^ (rr & 3)) << 3));
    }
    #pragma unroll
    for (int ti = 0; ti < 2; ++ti) {
      int ra = ((((wv << 1) + ti) << 4) + m16);
      shortx8 a = *(const shortx8*)(Ab + ra * 32 + ((q ^ (ra & 3)) << 3));
      #pragma unroll
      for (int nt = 0; nt < 4; ++nt)
        acc[ti][nt] = __builtin_amdgcn_mfma_f32_16x16x32_bf16(a, bfr[nt], acc[ti][nt], 0, 0, 0);
    }
    __syncthreads();
  }

  // epilogue: write TRANSPOSED bf16 (D col=lane&15 -> c; row=q*4+r -> j)
  #pragma unroll
  for (int ti = 0; ti < 2; ++ti) {
    int j0 = m0 + (((wv << 1) + ti) << 4) + (q << 2);
    if (j0 < total) {
      #pragma unroll
      for (int nt = 0; nt < 4; ++nt) {
        int cr = bandbase + (nt << 4) + m16;
        floatx4 d = acc[ti][nt];
        ushort4 u;
        u.x = f2bf(d[0]); u.y = f2bf(d[1]); u.z = f2bf(d[2]); u.w = f2bf(d[3]);
        *(ushort4*)(xwT + (size_t)cr * total + j0) = u;
      }
    }
  }
}

// ---------------- chunked phase B: out += mean_h(alpha_h @ XW_h) + bias ----
// No LDS, no barriers: B-fragment (8 consecutive j at fixed c) is a direct
// contiguous 16-B global read from xwT chunk; A-fragment is alpha.
// Pad j-slots: alpha == 0 there, xwT defined (zeroed X pads) -> safe.
#define MTW 5
__global__ __launch_bounds__(256, 3) void k_phaseB(
    const unsigned short* __restrict__ xwT, const unsigned short* __restrict__ alpha,
    const int* __restrict__ aoff, const int* __restrict__ off,
    const int* __restrict__ natoms, const int* __restrict__ meta,
    const float* __restrict__ bias, unsigned short* __restrict__ xout,
    int C, int cb0, int ncb) {
  int pitch = meta[0];
  int i = blockIdx.x / BB;       // 0..ncb-1
  int b = blockIdx.x - i * BB;
  int c0 = (cb0 + i) << 6;
  int n = natoms[b];
  if (n == 0) return;
  int ob = off[b];
  size_t ab = (size_t)aoff[b];
  int tid = threadIdx.x;
  int wv = tid >> 6, lane = tid & 63;
  int m16 = lane & 15, q = lane >> 4;
  int mtn = (n + 15) >> 4;
  int jmax = mtn << 4;
  int ktn = (n + 31) >> 5;
  int kext = ktn << 5;
  size_t hstride = (size_t)jmax * kext;

  floatx4 acc[MTW][4];
  #pragma unroll
  for (int t_i = 0; t_i < MTW; ++t_i)
    #pragma unroll
    for (int nt = 0; nt < 4; ++nt) acc[t_i][nt] = (floatx4)0.f;

  for (int h = 0; h < 3; ++h) {
    const unsigned short* ap = alpha + ab + (size_t)h * hstride + (q << 3);
    const unsigned short* xb = xwT + (size_t)(((h * ncb + i) << 6) + m16) * pitch + ob + (q << 3);
    #pragma unroll 2
    for (int k0p = 0; k0p < kext; k0p += 32) {
      shortx8 tb[4];
      #pragma unroll
      for (int nt = 0; nt < 4; ++nt)
        tb[nt] = *(const shortx8*)(xb + (size_t)(nt << 4) * pitch + k0p);
      #pragma unroll
      for (int t_i = 0; t_i < MTW; ++t_i) {
        int mt = wv + (t_i << 2);
        if (mt < mtn) {
          shortx8 af = *(const shortx8*)(ap + (size_t)((mt << 4) + m16) * kext + k0p);
          #pragma unroll
          for (int nt = 0; nt < 4; ++nt)
            acc[t_i][nt] = __builtin_amdgcn_mfma_f32_16x16x32_bf16(af, tb[nt], acc[t_i][nt], 0, 0, 0);
        }
      }
    }
  }
  float bq[4];
  #pragma unroll
  for (int nt = 0; nt < 4; ++nt) bq[nt] = bias[c0 + (nt << 4) + m16];
  const float inv3 = 1.f / 3.f;
  #pragma unroll
  for (int t_i = 0; t_i < MTW; ++t_i) {
    int mt = wv + (t_i << 2);
    if (mt < mtn) {
      #pragma unroll
      for (int nt = 0; nt < 4; ++nt) {
        floatx4 d = acc[t_i][nt];
        int cidx = c0 + (nt << 4) + m16;
        #pragma unroll
        for (int r = 0; r < 4; ++r) {
          int ii = (mt << 4) + (q << 2) + r;
          if (ii < n) xout[(size_t)(ob + ii) * C + cidx] = f2bf(d[r] * inv3 + bq[nt]);
        }
      }
    }
  }
  // zero pad rows [n, kext) of this cblk (keeps next stage's input defined)
  for (int e = tid; e < ((kext - n) << 4); e += 256) {
    int row = n + (e >> 4);
    int c = c0 + ((e & 15) << 2);
    ushort4 z4; z4.x = z4.y = z4.z = z4.w = 0;
    *(ushort4*)(xout + (size_t)(ob + row) * C + c) = z4;
  }
}

// ===== merged readout + head MLP: block/graph, 512 threads =================
__global__ __launch_bounds__(512) void k_feat_head(
    const unsigned short* __restrict__ x2, const float* __restrict__ pad2,
    const int* __restrict__ off, const int* __restrict__ natoms,
    const float* __restrict__ sgx, const float* __restrict__ latx,
    const float* __restrict__ W1, const float* __restrict__ b1,
    const float* __restrict__ g1, const float* __restrict__ be1,
    const float* __restrict__ m1, const float* __restrict__ v1,
    const float* __restrict__ W2, const float* __restrict__ b2,
    const float* __restrict__ g2, const float* __restrict__ be2,
    const float* __restrict__ m2, const float* __restrict__ v2,
    const float* __restrict__ W3, const float* __restrict__ b3,
    float* __restrict__ out) {
  int b = blockIdx.x, tid = threadIdx.x;  // 512
  int wv8 = tid >> 6, lane = tid & 63;
  int n = natoms[b], ob = off[b];
  __shared__ float part[8][256];
  __shared__ float f[PIN];
  __shared__ float h1[P1];
  __shared__ float h2[P1];
  __shared__ float red[512];
  float a0 = 0.f, a1 = 0.f, a2 = 0.f, a3 = 0.f;
  for (int r = wv8; r < n; r += 8) {
    uint2 raw = *(const uint2*)(x2 + (size_t)(ob + r) * C2 + (lane << 2));
    unsigned short us[4];
    *(uint2*)us = raw;
    a0 += bf2f(us[0]); a1 += bf2f(us[1]); a2 += bf2f(us[2]); a3 += bf2f(us[3]);
  }
  {
    float4 p = make_float4(a0, a1, a2, a3);
    *(float4*)&part[wv8][lane << 2] = p;
  }
  __syncthreads();
  if (tid < 256) {
    float s = 0.f;
    #pragma unroll
    for (int w = 0; w < 8; ++w) s += part[w][tid];
    f[tid] = s + (float)(NMAX - n) * pad2[tid];
  } else if (tid < 320) {
    f[tid] = sgx[b * SGE + (tid - 256)];
  } else if (tid < 448) {
    f[tid] = latx[b * LATH + (tid - 320)];
  }
  __syncthreads();
  {
    int o = tid;
    float acc = b1[o];
    for (int k = 0; k < PIN; ++k) acc += f[k] * W1[k * P1 + o];
    acc = (acc - m1[o]) * g1[o] * rsqrtf(v1[o] + EPSB) + be1[o];
    h1[o] = acc >= 0.f ? acc : 0.2f * acc;
  }
  __syncthreads();
  {
    int o = tid;
    float acc = b2[o];
    for (int k = 0; k < P1; ++k) acc += h1[k] * W2[k * P1 + o];
    acc = (acc - m2[o]) * g2[o] * rsqrtf(v2[o] + EPSB) + be2[o];
    h2[o] = acc >= 0.f ? acc : 0.2f * acc;
  }
  __syncthreads();
  red[tid] = h2[tid] * W3[tid];
  __syncthreads();
  for (int s = 256; s > 0; s >>= 1) {
    if (tid < s) red[tid] += red[tid + s];
    __syncthreads();
  }
  if (tid == 0) out[b] = red[0] + b3[0];
}

extern "C" void kernel_launch(void* const* d_in, const int* in_sizes, int n_in,
                              void* d_out, int out_size, void* d_ws, size_t ws_size,
                              hipStream_t stream) {
  const int*   comp       = (const int*)d_in[0];
  const int*   sg         = (const int*)d_in[1];
  const float* lat        = (const float*)d_in[2];
  const int*   period_idx = (const int*)d_in[3];
  const int*   group_idx  = (const int*)d_in[4];
  const float* sg_emb     = (const float*)d_in[5];
  const float* lat_W1     = (const float*)d_in[6];
  const float* lat_b1     = (const float*)d_in[7];
  const float* lat_bn1_g  = (const float*)d_in[8];
  const float* lat_bn1_b  = (const float*)d_in[9];
  const float* lat_bn1_m  = (const float*)d_in[10];
  const float* lat_bn1_v  = (const float*)d_in[11];
  const float* lat_W2     = (const float*)d_in[12];
  const float* lat_b2     = (const float*)d_in[13];
  const float* lat_bn2_g  = (const float*)d_in[14];
  const float* lat_bn2_b  = (const float*)d_in[15];
  const float* lat_bn2_m  = (const float*)d_in[16];
  const float* lat_bn2_v  = (const float*)d_in[17];
  const float* z_emb      = (const float*)d_in[18];
  const float* period_t   = (const float*)d_in[19];
  const float* group_t    = (const float*)d_in[20];
  const float* props      = (const float*)d_in[21];
  const float* W_props    = (const float*)d_in[22];
  const float* b_props    = (const float*)d_in[23];
  const float* W_phys     = (const float*)d_in[24];
  const float* b_phys     = (const float*)d_in[25];
  const float* gat1_W     = (const float*)d_in[26];
  const float* gat1_as    = (const float*)d_in[27];
  const float* gat1_ad    = (const float*)d_in[28];
  const float* gat1_b     = (const float*)d_in[29];
  const float* gat2_W     = (const float*)d_in[30];
  const float* gat2_as    = (const float*)d_in[31];
  const float* gat2_ad    = (const float*)d_in[32];
  const float* gat2_b     = (const float*)d_in[33];
  const float* pW1        = (const float*)d_in[34];
  const float* pb1        = (const float*)d_in[35];
  const float* pbn1_g     = (const float*)d_in[36];
  const float* pbn1_b     = (const float*)d_in[37];
  const float* pbn1_m     = (const float*)d_in[38];
  const float* pbn1_v     = (const float*)d_in[39];
  const float* pW2        = (const float*)d_in[40];
  const float* pb2        = (const float*)d_in[41];
  const float* pbn2_g     = (const float*)d_in[42];
  const float* pbn2_b     = (const float*)d_in[43];
  const float* pbn2_m     = (const float*)d_in[44];
  const float* pbn2_v     = (const float*)d_in[45];
  const float* pW3        = (const float*)d_in[46];
  const float* pb3        = (const float*)d_in[47];

  float* ws = (float*)d_ws;
  const size_t o_sgx  = 0;
  const size_t o_latx = o_sgx  + (size_t)BB * SGE;
  const size_t o_nat  = o_latx + (size_t)BB * LATH;
  const size_t o_off  = o_nat  + BB;
  const size_t o_aoff = o_off  + BB;
  const size_t o_meta = o_aoff + BB;
  const size_t o_z    = o_meta + 64;
  const size_t o_phys = o_z    + (size_t)BB * NMAX;
  const size_t o_wsv1 = o_phys + (size_t)NEL * 256;
  const size_t o_wdv1 = o_wsv1 + (size_t)C1 * 3;
  const size_t o_wsv2 = o_wdv1 + (size_t)C1 * 3;
  const size_t o_wdv2 = o_wsv2 + (size_t)C1 * 3;
  const size_t o_asrc = o_wdv2 + (size_t)C1 * 3;
  const size_t o_adst = o_asrc + (size_t)BB * NMAX * 3;
  const size_t o_pad2 = o_adst + (size_t)BB * NMAX * 3;
  const size_t o_zero = o_pad2 + 256;
  const size_t o_wt1  = o_zero + 256;
  const size_t o_wt2  = o_wt1  + (size_t)(3 * C1) * PIN / 2;
  const size_t o_x0   = o_wt2  + (size_t)(3 * C2) * C1 / 2;
  const size_t o_x1   = o_x0   + (size_t)XROWCAP * PIN / 2;  // 9.86M floats
  const size_t o_alph = o_x1   + (size_t)XROWCAP * PIN / 2;
  const size_t o_xwt  = o_alph + 9500000;                    // alpha ~35.4 MB actual
  // xwT chunk: 384 rows x XROWCAP shorts = 33.8 MB -> total ws ~155 MB

  float* sgx    = ws + o_sgx;
  float* latx   = ws + o_latx;
  int*   natoms = (int*)(ws + o_nat);
  int*   off    = (int*)(ws + o_off);
  int*   aoff   = (int*)(ws + o_aoff);
  int*   meta   = (int*)(ws + o_meta);
  int*   z      = (int*)(ws + o_z);
  float* physpe = ws + o_phys;
  float* wsv1   = ws + o_wsv1;
  float* wdv1   = ws + o_wdv1;
  float* wsv2   = ws + o_wsv2;
  float* wdv2   = ws + o_wdv2;
  float* asrc   = ws + o_asrc;
  float* adst   = ws + o_adst;
  float* pad2   = ws + o_pad2;
  float* zerobuf = ws + o_zero;
  unsigned short* wt1   = (unsigned short*)(ws + o_wt1);
  unsigned short* wt2   = (unsigned short*)(ws + o_wt2);
  unsigned short* x0    = (unsigned short*)(ws + o_x0);
  unsigned short* x1    = (unsigned short*)(ws + o_x1);
  unsigned short* x2    = x0;
  unsigned short* xwT   = (unsigned short*)(ws + o_xwt);
  unsigned short* alpha = (unsigned short*)(ws + o_alph);

  const int ALG = BB * 3 * MTMAX;

  k_setup<<<SETUP_GRID, 256, 0, stream>>>(
      comp, sg, lat, sg_emb,
      lat_W1, lat_b1, lat_bn1_g, lat_bn1_b, lat_bn1_m, lat_bn1_v,
      lat_W2, lat_b2, lat_bn2_g, lat_bn2_b, lat_bn2_m, lat_bn2_v,
      period_idx, group_idx, z_emb, period_t, group_t, props,
      W_props, b_props, W_phys, b_phys,
      gat1_W, gat1_as, gat1_ad, gat1_b,
      gat2_W, gat2_as, gat2_ad, gat2_b,
      sgx, latx, z, natoms, off, aoff, meta, zerobuf, physpe,
      wt1, wt2, wsv1, wdv1, wsv2, wdv2, pad2);

  k_nodep<<<BB, 256, 0, stream>>>(z, off, natoms, physpe, latx, sgx, x0);

  // ---- GAT layer 1 (C1=448 -> 7 cblks in chunks of 2,2,2,1) ----
  k_av2<<<1024, 256, 0, stream>>>(x0, wsv1, wdv1, off, natoms, asrc, adst, PIN);
  k_alpha<<<ALG, 256, 0, stream>>>(asrc, adst, off, natoms, aoff, alpha);
  {
    const int cbs[4] = {0, 2, 4, 6};
    const int ncbs[4] = {2, 2, 2, 1};
    for (int c = 0; c < 4; ++c) {
      k_gemm<<<GJT * 3 * ncbs[c], 256, 0, stream>>>(x0, wt1, meta, zerobuf,
          xwT, C1, cbs[c], ncbs[c]);
      k_phaseB<<<ncbs[c] * BB, 256, 0, stream>>>(xwT, alpha, aoff, off, natoms,
          meta, gat1_b, x1, C1, cbs[c], ncbs[c]);
    }
  }

  // ---- GAT layer 2 (C2=256 -> 4 cblks in chunks of 2,2) ----
  k_av2<<<1024, 256, 0, stream>>>(x1, wsv2, wdv2, off, natoms, asrc, adst, C1);
  k_alpha<<<ALG, 256, 0, stream>>>(asrc, adst, off, natoms, aoff, alpha);
  for (int c = 0; c < 2; ++c) {
    k_gemm<<<GJT * 6, 256, 0, stream>>>(x1, wt2, meta, zerobuf,
        xwT, C2, c * 2, 2);
    k_phaseB<<<2 * BB, 256, 0, stream>>>(xwT, alpha, aoff, off, natoms,
        meta, gat2_b, x2, C2, c * 2, 2);
  }

  // ---- merged readout + head ----
  k_feat_head<<<BB, 512, 0, stream>>>(x2, pad2, off, natoms, sgx, latx,
      pW1, pb1, pbn1_g, pbn1_b, pbn1_m, pbn1_v,
      pW2, pb2, pbn2_g, pbn2_b, pbn2_m, pbn2_v,
      pW3, pb3, (float*)d_out);
}

// Round 6
// 960.911 us; speedup vs baseline: 1.0489x; 1.0489x over previous
//
#include <hip/hip_runtime.h>
#include <math.h>

#define BB 256
#define NEL 90
#define NMAX 270
#define C1 448
#define C2 256
#define PIN 448
#define LATH 128
#define SGE 64
#define P1 512
#define EPSB 1e-5f

#define XROWCAP 44032           /* row capacity of x/xwT buffers (total32 ~38.6k fixed-seed) */
#define GJT (XROWCAP / 128)     /* 344 GEMM j-tiles */

typedef short shortx8 __attribute__((ext_vector_type(8)));
typedef float floatx4 __attribute__((ext_vector_type(4)));

__device__ __forceinline__ float bf2f(unsigned short u) {
  return __uint_as_float(((unsigned)u) << 16);
}
__device__ __forceinline__ unsigned short f2bf(float f) {
  unsigned x = __float_as_uint(f);
  unsigned r = (x + 0x7fffu + ((x >> 16) & 1u)) >> 16;
  return (unsigned short)r;
}
// async 16B global->LDS (gfx950). LDS dest: wave-uniform base + lane*16.
__device__ __forceinline__ void gld16(const void* g, void* l) {
  __builtin_amdgcn_global_load_lds(
      (const __attribute__((address_space(1))) unsigned int*)g,
      (__attribute__((address_space(3))) unsigned int*)l, 16, 0, 0);
}

// ================= mega prologue: prep | scan | physpe | wprep x2 | fold x2 | pad
#define NB_PREP  BB
#define NB_SCAN  1
#define NB_PHYS  NEL
#define NB_WP1   (14 * 42)
#define NB_WP2   (14 * 24)
#define NB_FOLD  112
#define NB_PAD   64
#define SETUP_GRID (NB_PREP + NB_SCAN + NB_PHYS + NB_WP1 + NB_WP2 + 2 * NB_FOLD + NB_PAD)

__global__ __launch_bounds__(256) void k_setup(
    const int* __restrict__ comp, const int* __restrict__ sg, const float* __restrict__ lat,
    const float* __restrict__ sg_emb,
    const float* __restrict__ lW1, const float* __restrict__ lb1,
    const float* __restrict__ lg1, const float* __restrict__ lbe1,
    const float* __restrict__ lm1, const float* __restrict__ lv1,
    const float* __restrict__ lW2, const float* __restrict__ lb2,
    const float* __restrict__ lg2, const float* __restrict__ lbe2,
    const float* __restrict__ lm2, const float* __restrict__ lv2,
    const int* __restrict__ period_idx, const int* __restrict__ group_idx,
    const float* __restrict__ z_emb, const float* __restrict__ period_t,
    const float* __restrict__ group_t, const float* __restrict__ props,
    const float* __restrict__ Wp, const float* __restrict__ bp,
    const float* __restrict__ Wphys, const float* __restrict__ bphys,
    const float* __restrict__ gat1_W, const float* __restrict__ gat1_as,
    const float* __restrict__ gat1_ad, const float* __restrict__ gat1_b,
    const float* __restrict__ gat2_W, const float* __restrict__ gat2_as,
    const float* __restrict__ gat2_ad, const float* __restrict__ gat2_b,
    float* __restrict__ sgx, float* __restrict__ latx, int* __restrict__ z,
    int* __restrict__ natoms, int* __restrict__ off, int* __restrict__ aoff,
    int* __restrict__ meta,
    float* __restrict__ zerobuf, float* __restrict__ physpe,
    unsigned short* __restrict__ wt1, unsigned short* __restrict__ wt2,
    float* __restrict__ wsv1, float* __restrict__ wdv1,
    float* __restrict__ wsv2, float* __restrict__ wdv2, float* __restrict__ pad2) {
  int r = blockIdx.x;
  int tid = threadIdx.x;
  int wv = tid >> 6, lane = tid & 63;

  if (r < NB_PREP) {  // ---- prep (z, sgx, latx) ----
    int b = r;
    __shared__ int cum[NEL];
    __shared__ float hbuf[LATH];
    __shared__ float latl[6];
    if (tid == 0) {
      int s = 0;
      for (int e = 0; e < NEL; ++e) { s += comp[b * NEL + e]; cum[e] = s; }
    }
    if (tid < 6) latl[tid] = lat[b * 6 + tid];
    __syncthreads();
    int n = cum[NEL - 1];
    for (int t = tid; t < NMAX; t += 256) {
      int zz = -1;
      if (t < n) {
        for (int e = 0; e < NEL; ++e) { if (cum[e] > t) { zz = e; break; } }
      }
      z[b * NMAX + t] = zz;
    }
    if (tid < SGE) sgx[b * SGE + tid] = sg_emb[sg[b] * SGE + tid];
    if (tid < LATH) {
      float acc = lb1[tid];
      for (int k = 0; k < 6; ++k) acc += latl[k] * lW1[k * LATH + tid];
      acc = (acc - lm1[tid]) * lg1[tid] * rsqrtf(lv1[tid] + EPSB) + lbe1[tid];
      hbuf[tid] = acc;
    }
    __syncthreads();
    if (tid < LATH) {
      float acc = lb2[tid];
      for (int k = 0; k < LATH; ++k) acc += hbuf[k] * lW2[k * LATH + tid];
      acc = (acc - lm2[tid]) * lg2[tid] * rsqrtf(lv2[tid] + EPSB) + lbe2[tid];
      latx[b * LATH + tid] = acc;
    }
    return;
  }
  r -= NB_PREP;
  if (r < NB_SCAN) {  // ---- scans (natoms, off32 kext-padded, aoff) + zero page
    __shared__ int sh[BB];
    zerobuf[tid] = 0.f;
    int v0 = 0;
    for (int e = 0; e < NEL; ++e) v0 += comp[tid * NEL + e];
    natoms[tid] = v0;
    int kx = ((v0 + 31) >> 5) << 5;   // kext-aligned row window per graph
    sh[tid] = kx;
    for (int d = 1; d < BB; d <<= 1) {
      __syncthreads();
      int v = (tid >= d) ? sh[tid - d] : 0;
      __syncthreads();
      sh[tid] += v;
    }
    __syncthreads();
    off[tid] = sh[tid] - kx;
    if (tid == BB - 1) meta[0] = sh[tid];   // total32 = padded row count
    __syncthreads();
    int sz = 3 * ((((v0 + 15) >> 4) << 4)) * ((((v0 + 31) >> 5) << 5));
    sh[tid] = sz;
    for (int d = 1; d < BB; d <<= 1) {
      __syncthreads();
      int v = (tid >= d) ? sh[tid - d] : 0;
      __syncthreads();
      sh[tid] += v;
    }
    __syncthreads();
    aoff[tid] = sh[tid] - sz;
    return;
  }
  r -= NB_SCAN;
  if (r < NB_PHYS) {  // ---- physpe rows ----
    int e = r;
    __shared__ float ph[128];
    if (tid < 32) ph[tid] = z_emb[e * 32 + tid];
    else if (tid < 64) ph[tid] = period_t[period_idx[e] * 32 + tid - 32];
    else if (tid < 96) ph[tid] = group_t[group_idx[e] * 32 + tid - 64];
    else if (tid < 128) {
      int j = tid - 96;
      float acc = bp[j];
      for (int k = 0; k < 20; ++k) acc += props[e * 20 + k] * Wp[k * 32 + j];
      ph[tid] = acc;
    }
    __syncthreads();
    float acc = bphys[tid];
    for (int k = 0; k < 128; ++k) acc += ph[k] * Wphys[k * 256 + tid];
    physpe[e * 256 + tid] = acc;
    return;
  }
  r -= NB_PHYS;
  if (r < NB_WP1 + NB_WP2) {  // ---- W transpose to bf16 W^T ----
    const float* W;
    unsigned short* Wt;
    int NC3, bx, by;
    if (r < NB_WP1) { W = gat1_W; Wt = wt1; NC3 = 3 * C1; bx = r % 14; by = r / 14; }
    else { int r2 = r - NB_WP1; W = gat2_W; Wt = wt2; NC3 = 3 * C2; bx = r2 % 14; by = r2 / 14; }
    int k0 = bx << 5, c0 = by << 5;
    __shared__ float ts[32][33];
    int e4 = tid << 2;
    int kk = e4 >> 5, cc = e4 & 31;
    float4 v = *(const float4*)(W + (size_t)(k0 + kk) * NC3 + c0 + cc);
    ts[kk][cc] = v.x; ts[kk][cc + 1] = v.y; ts[kk][cc + 2] = v.z; ts[kk][cc + 3] = v.w;
    __syncthreads();
    int c2 = tid & 31, kg = tid >> 5;
    ushort4 u;
    u.x = f2bf(ts[kg * 4 + 0][c2]); u.y = f2bf(ts[kg * 4 + 1][c2]);
    u.z = f2bf(ts[kg * 4 + 2][c2]); u.w = f2bf(ts[kg * 4 + 3][c2]);
    *(ushort4*)(Wt + (size_t)(c0 + c2) * 448 + k0 + (kg << 2)) = u;
    return;
  }
  r -= NB_WP1 + NB_WP2;
  if (r < 2 * NB_FOLD) {  // ---- fold a_s/a_d through W ----
    const float* W; const float* as_; const float* ad_;
    float* wsv; float* wdv; int NC3, C, kb;
    if (r < NB_FOLD) { W = gat1_W; as_ = gat1_as; ad_ = gat1_ad; wsv = wsv1; wdv = wdv1; NC3 = 3 * C1; C = C1; kb = r << 2; }
    else { int r2 = r - NB_FOLD; W = gat2_W; as_ = gat2_as; ad_ = gat2_ad; wsv = wsv2; wdv = wdv2; NC3 = 3 * C2; C = C2; kb = r2 << 2; }
    int k = kb + wv;
    for (int h = 0; h < 3; ++h) {
      float ss = 0.f, sd = 0.f;
      for (int c = lane; c < C; c += 64) {
        float wvv = W[(size_t)k * NC3 + h * C + c];
        ss += wvv * as_[h * C + c];
        sd += wvv * ad_[h * C + c];
      }
      for (int o = 32; o > 0; o >>= 1) { ss += __shfl_xor(ss, o); sd += __shfl_xor(sd, o); }
      if (lane == 0) { wsv[k * 3 + h] = ss; wdv[k * 3 + h] = sd; }
    }
    return;
  }
  r -= 2 * NB_FOLD;
  {  // ---- pad-row value after layer 2 ----
    int c = (r << 2) + wv;
    float s = 0.f;
    for (int k = lane; k < C1; k += 64) {
      const float* wr = gat2_W + (size_t)k * (3 * C2) + c;
      s += gat1_b[k] * (wr[0] + wr[C2] + wr[2 * C2]);
    }
    for (int o = 32; o > 0; o >>= 1) s += __shfl_xor(s, o);
    if (lane == 0) pad2[c] = s * (1.f / 3.f) + gat2_b[c];
  }
}

// ---------------- packed node features x0 [total32,448] bf16 + zero pads ---
__global__ __launch_bounds__(256) void k_nodep(
    const int* __restrict__ z, const int* __restrict__ off, const int* __restrict__ natoms,
    const float* __restrict__ physpe, const float* __restrict__ latx,
    const float* __restrict__ sgx, unsigned short* __restrict__ x0) {
  int b = blockIdx.x;
  int n = natoms[b], ob = off[b];
  int tid = threadIdx.x;
  __shared__ int zl[NMAX];
  for (int t = tid; t < n; t += 256) zl[t] = z[b * NMAX + t];
  __syncthreads();
  int items = n * 56;
  for (int e = tid; e < items; e += 256) {
    int t = e / 56, c8 = (e - t * 56) << 3;
    int zt = zl[t];
    float v[8];
    if (c8 < 256) {
      float4 a = *(const float4*)(physpe + zt * 256 + c8);
      float4 c = *(const float4*)(physpe + zt * 256 + c8 + 4);
      v[0] = a.x; v[1] = a.y; v[2] = a.z; v[3] = a.w;
      v[4] = c.x; v[5] = c.y; v[6] = c.z; v[7] = c.w;
    } else if (c8 < 384) {
      float4 a = *(const float4*)(latx + b * LATH + c8 - 256);
      float4 c = *(const float4*)(latx + b * LATH + c8 - 252);
      v[0] = a.x; v[1] = a.y; v[2] = a.z; v[3] = a.w;
      v[4] = c.x; v[5] = c.y; v[6] = c.z; v[7] = c.w;
    } else {
      float4 a = *(const float4*)(sgx + b * SGE + c8 - 384);
      float4 c = *(const float4*)(sgx + b * SGE + c8 - 380);
      v[0] = a.x; v[1] = a.y; v[2] = a.z; v[3] = a.w;
      v[4] = c.x; v[5] = c.y; v[6] = c.z; v[7] = c.w;
    }
    unsigned short u[8];
    #pragma unroll
    for (int i = 0; i < 8; ++i) u[i] = f2bf(v[i]);
    *(uint4*)(x0 + (size_t)(ob + t) * PIN + c8) = *(uint4*)u;
  }
  // zero pad rows [n, kext) so GEMM's XW of pad rows is defined (NaN-safe)
  int kext = ((n + 31) >> 5) << 5;
  int pitems = (kext - n) * 56;
  for (int e = tid; e < pitems; e += 256) {
    int rr = e / 56, c8 = (e - rr * 56) << 3;
    uint4 z4; z4.x = z4.y = z4.z = z4.w = 0u;
    *(uint4*)(x0 + (size_t)(ob + n + rr) * PIN + c8) = z4;
  }
}

// ---------------- asrc/adst: one WAVE per row (coalesced) ----------------
__global__ __launch_bounds__(256) void k_av2(
    const unsigned short* __restrict__ x, const float* __restrict__ wsv,
    const float* __restrict__ wdv, const int* __restrict__ off,
    const int* __restrict__ natoms, float* __restrict__ asrc,
    float* __restrict__ adst, int K) {
  __shared__ float sw[C1 * 3], dw[C1 * 3];
  int tid = threadIdx.x;
  for (int e = tid; e < K * 3; e += 256) { sw[e] = wsv[e]; dw[e] = wdv[e]; }
  __syncthreads();
  int total = off[BB - 1] + natoms[BB - 1];
  int wv = tid >> 6, lane = tid & 63;
  int nk8 = K >> 3;
  int stride = gridDim.x << 2;
  for (int row = (blockIdx.x << 2) + wv; row < total; row += stride) {
    float s0 = 0.f, s1 = 0.f, s2 = 0.f, d0 = 0.f, d1 = 0.f, d2 = 0.f;
    if (lane < nk8) {
      uint4 raw = *(const uint4*)(x + (size_t)row * K + (lane << 3));
      unsigned short us[8];
      *(uint4*)us = raw;
      #pragma unroll
      for (int u = 0; u < 8; ++u) {
        float xv = bf2f(us[u]);
        int kb = ((lane << 3) + u) * 3;
        s0 += xv * sw[kb + 0]; s1 += xv * sw[kb + 1]; s2 += xv * sw[kb + 2];
        d0 += xv * dw[kb + 0]; d1 += xv * dw[kb + 1]; d2 += xv * dw[kb + 2];
      }
    }
    #pragma unroll
    for (int o = 32; o > 0; o >>= 1) {
      s0 += __shfl_xor(s0, o); s1 += __shfl_xor(s1, o); s2 += __shfl_xor(s2, o);
      d0 += __shfl_xor(d0, o); d1 += __shfl_xor(d1, o); d2 += __shfl_xor(d2, o);
    }
    if (lane == 0) {
      asrc[row * 3 + 0] = s0; asrc[row * 3 + 1] = s1; asrc[row * 3 + 2] = s2;
      adst[row * 3 + 0] = d0; adst[row * 3 + 1] = d1; adst[row * 3 + 2] = d2;
    }
  }
}

// ---------------- alpha materialization (sharded): one (b,h,mtile)/block ---
#define MTMAX 17
__global__ __launch_bounds__(256) void k_alpha(
    const float* __restrict__ asrc, const float* __restrict__ adst,
    const int* __restrict__ off, const int* __restrict__ natoms,
    const int* __restrict__ aoff, unsigned short* __restrict__ alpha) {
  int bid = blockIdx.x;
  int b = bid & (BB - 1);
  int hm = bid >> 8;
  int h = hm % 3;
  int mt = hm / 3;
  int n = natoms[b];
  if (n == 0) return;
  int mtn = (n + 15) >> 4;
  if (mt >= mtn) return;
  int ktn = (n + 31) >> 5;
  int rext = mtn << 4, kext = ktn << 5;
  int ob = off[b];
  size_t ab = (size_t)aoff[b] + (size_t)h * rext * kext;
  int tid = threadIdx.x;
  int wv = tid >> 6, lane = tid & 63;
  __shared__ float asl[288];
  for (int j = tid; j < kext; j += 256)
    asl[j] = (j < n) ? asrc[(ob + j) * 3 + h] : 0.f;
  __syncthreads();
  #pragma unroll
  for (int r = 0; r < 4; ++r) {
    int i = (mt << 4) + (wv << 2) + r;
    unsigned short* rowp = alpha + ab + (size_t)i * kext;
    if (i >= n) {
      for (int j = lane; j < kext; j += 64) rowp[j] = 0;
      continue;
    }
    float ad = adst[(ob + i) * 3 + h];
    float m = -1e30f;
    for (int j = lane; j < n; j += 64) {
      float sc = asl[j] + ad;
      sc = fmaxf(sc, 0.2f * sc);
      m = fmaxf(m, sc);
    }
    for (int o = 32; o > 0; o >>= 1) m = fmaxf(m, __shfl_xor(m, o));
    float s = 0.f;
    for (int j = lane; j < n; j += 64) {
      float sc = asl[j] + ad;
      sc = fmaxf(sc, 0.2f * sc);
      s += __expf(sc - m);
    }
    for (int o = 32; o > 0; o >>= 1) s += __shfl_xor(s, o);
    float rs = 1.f / s;
    for (int j = lane; j < kext; j += 64) {
      float v = 0.f;
      if (j < n) {
        float sc = asl[j] + ad;
        sc = fmaxf(sc, 0.2f * sc);
        v = __expf(sc - m) * rs;
      }
      rowp[j] = f2bf(v);
    }
  }
}

// ---------------- chunked dense GEMM: xwT rows = chunk cols, transposed ----
// Chunk covers ncb cblks (64 cols each) x 3 heads -> 3*ncb N-tiles.
// xwT chunk layout: [(h*ncb + i)*64 + local_c][total] bf16, pitch = total32.
// BM=128 BN=64 BK=32, gld16 dbuf, XOR-swizzled chunks (both-sides involution).
// Epilogue (R6): transpose the 64x128 output tile through LDS (row pad +4
// shorts for bank spread), then write 64-B contiguous runs per c-row.
// The old direct scatter wrote ushort4 at stride `total` -> every 128-B
// line written partially by 2 blocks (RMW FETCH inflation).
__global__ __launch_bounds__(256, 4) void k_gemm(
    const unsigned short* __restrict__ X, const unsigned short* __restrict__ W,
    const int* __restrict__ meta, const float* __restrict__ zerobuf,
    unsigned short* __restrict__ xwT, int C, int cb0, int ncb) {
  int total = meta[0];
  int NBT = 3 * ncb;
  int mb = blockIdx.x / NBT;
  int m0 = mb << 7;
  if (m0 >= total) return;
  int nb = blockIdx.x - mb * NBT;
  int h = nb / ncb;
  int i = nb - h * ncb;
  int colbase = h * C + ((cb0 + i) << 6);   // row base in Wt
  int bandbase = nb << 6;                    // row base in xwT chunk
  int tid = threadIdx.x;
  int wv = tid >> 6, lane = tid & 63;
  int m16 = lane & 15, q = lane >> 4;

  // 24 KB LDS: As = smem[0..8192), Bs = smem[8192..12288) (shorts).
  // Epilogue reuses smem as 64 x 132 transpose buffer (8448 shorts).
  __shared__ unsigned short smem[12288];
  unsigned short* As0 = smem;
  unsigned short* As1 = smem + 4096;
  unsigned short* Bs0 = smem + 8192;
  unsigned short* Bs1 = smem + 10240;

  int l4 = lane >> 2, ci = lane & 3;
  int ra0 = (wv << 4) + l4;
  int ra1 = ra0 + 64;
  int rb  = (wv << 4) + l4;
  // pre-swizzled global sources (LDS dest linear; read applies same XOR)
  const unsigned short* asrc0 = (m0 + ra0 < total)
      ? (X + (size_t)(m0 + ra0) * 448 + ((ci ^ (ra0 & 3)) << 3))
      : (const unsigned short*)zerobuf;
  const unsigned short* asrc1 = (m0 + ra1 < total)
      ? (X + (size_t)(m0 + ra1) * 448 + ((ci ^ (ra1 & 3)) << 3))
      : (const unsigned short*)zerobuf;
  const unsigned short* bsrc = W + (size_t)(colbase + rb) * 448 + ((ci ^ (rb & 3)) << 3);

  floatx4 acc[2][4];
  #pragma unroll
  for (int ti = 0; ti < 2; ++ti)
    #pragma unroll
    for (int nt = 0; nt < 4; ++nt) acc[ti][nt] = (floatx4)0.f;

  gld16(asrc0, As0 + (wv << 9));
  gld16(asrc1, As0 + 2048 + (wv << 9));
  gld16(bsrc, Bs0 + (wv << 9));
  __syncthreads();

  #pragma unroll 2
  for (int s = 0; s < 14; ++s) {
    int cur = s & 1;
    unsigned short* Ab = cur ? As1 : As0;
    unsigned short* Bb = cur ? Bs1 : Bs0;
    if (s < 13) {
      int k1 = (s + 1) << 5;
      unsigned short* An = cur ? As0 : As1;
      unsigned short* Bn = cur ? Bs0 : Bs1;
      gld16(asrc0 + k1, An + (wv << 9));
      gld16(asrc1 + k1, An + 2048 + (wv << 9));
      gld16(bsrc + k1, Bn + (wv << 9));
    }
    shortx8 bfr[4];
    #pragma unroll
    for (int nt = 0; nt < 4; ++nt) {
      int rr = (nt << 4) + m16;
      bfr[nt] = *(const shortx8*)(Bb + rr * 32 + ((q ^ (rr & 3)) << 3));
    }
    #pragma unroll
    for (int ti = 0; ti < 2; ++ti) {
      int ra = ((((wv << 1) + ti) << 4) + m16);
      shortx8 a = *(const shortx8*)(Ab + ra * 32 + ((q ^ (ra & 3)) << 3));
      #pragma unroll
      for (int nt = 0; nt < 4; ++nt)
        acc[ti][nt] = __builtin_amdgcn_mfma_f32_16x16x32_bf16(a, bfr[nt], acc[ti][nt], 0, 0, 0);
    }
    __syncthreads();
  }

  // epilogue: transpose through LDS, coalesced row writes
  unsigned short* tb_ = smem;  // 64 x 132 shorts
  #pragma unroll
  for (int ti = 0; ti < 2; ++ti) {
    int j0 = (((wv << 1) + ti) << 4) + (q << 2);
    #pragma unroll
    for (int nt = 0; nt < 4; ++nt) {
      int c = (nt << 4) + m16;
      floatx4 d = acc[ti][nt];
      ushort4 u;
      u.x = f2bf(d[0]); u.y = f2bf(d[1]); u.z = f2bf(d[2]); u.w = f2bf(d[3]);
      *(ushort4*)(tb_ + c * 132 + j0) = u;
    }
  }
  __syncthreads();
  {
    int c = tid >> 2, js = (tid & 3) << 5;
    int jglob = m0 + js;
    if (jglob < total) {  // total and js are 32-aligned -> whole run valid
      unsigned short* dst = xwT + (size_t)(bandbase + c) * total + jglob;
      const unsigned short* src = tb_ + c * 132 + js;
      *(uint4*)(dst)      = *(const uint4*)(src);
      *(uint4*)(dst + 8)  = *(const uint4*)(src + 8);
      *(uint4*)(dst + 16) = *(const uint4*)(src + 16);
      *(uint4*)(dst + 24) = *(const uint4*)(src + 24);
    }
  }
}

// ---------------- chunked phase B: out += mean_h(alpha_h @ XW_h) + bias ----
// R6: grid split 3x over mtile groups (NMT) -- R5 was grid-starved
// (512 blocks = 2/CU, 8 waves/CU, 710 GB/s latency-bound). Each wave owns
// 2 mtiles; alpha read volume unchanged (rows partitioned by mt); xwT tb
// reads duplicated ~1.6x effective (early-outs below) but cache-resident.
// No LDS, no barriers.
#define NMT 3
__global__ __launch_bounds__(256, 4) void k_phaseB(
    const unsigned short* __restrict__ xwT, const unsigned short* __restrict__ alpha,
    const int* __restrict__ aoff, const int* __restrict__ off,
    const int* __restrict__ natoms, const int* __restrict__ meta,
    const float* __restrict__ bias, unsigned short* __restrict__ xout,
    int C, int cb0, int ncb) {
  int pitch = meta[0];
  int bid = blockIdx.x;
  int b = bid & (BB - 1);
  int g = bid >> 8;
  int i = g / NMT;
  int mg = g - i * NMT;
  int c0 = (cb0 + i) << 6;
  int n = natoms[b];
  if (n == 0) return;
  int mtn = (n + 15) >> 4;
  if ((mg << 3) >= mtn) return;   // whole block's mt range empty
  int ob = off[b];
  size_t ab = (size_t)aoff[b];
  int tid = threadIdx.x;
  int wv = tid >> 6, lane = tid & 63;
  int m16 = lane & 15, q = lane >> 4;
  int jmax = mtn << 4;
  int ktn = (n + 31) >> 5;
  int kext = ktn << 5;
  size_t hstride = (size_t)jmax * kext;

  int mt0 = (mg << 3) + (wv << 1);   // this wave: mt0, mt0+1 (covers 0..23)
  bool act0 = mt0 < mtn;
  bool act1 = mt0 + 1 < mtn;

  floatx4 acc[2][4];
  #pragma unroll
  for (int t_i = 0; t_i < 2; ++t_i)
    #pragma unroll
    for (int nt = 0; nt < 4; ++nt) acc[t_i][nt] = (floatx4)0.f;

  if (act0) {
    for (int h = 0; h < 3; ++h) {
      const unsigned short* ap = alpha + ab + (size_t)h * hstride + (q << 3);
      const unsigned short* xb = xwT + (size_t)(((h * ncb + i) << 6) + m16) * pitch + ob + (q << 3);
      #pragma unroll 2
      for (int k0p = 0; k0p < kext; k0p += 32) {
        shortx8 tb[4];
        #pragma unroll
        for (int nt = 0; nt < 4; ++nt)
          tb[nt] = *(const shortx8*)(xb + (size_t)(nt << 4) * pitch + k0p);
        {
          shortx8 af = *(const shortx8*)(ap + (size_t)((mt0 << 4) + m16) * kext + k0p);
          #pragma unroll
          for (int nt = 0; nt < 4; ++nt)
            acc[0][nt] = __builtin_amdgcn_mfma_f32_16x16x32_bf16(af, tb[nt], acc[0][nt], 0, 0, 0);
        }
        if (act1) {
          shortx8 af = *(const shortx8*)(ap + (size_t)(((mt0 + 1) << 4) + m16) * kext + k0p);
          #pragma unroll
          for (int nt = 0; nt < 4; ++nt)
            acc[1][nt] = __builtin_amdgcn_mfma_f32_16x16x32_bf16(af, tb[nt], acc[1][nt], 0, 0, 0);
        }
      }
    }
  }
  float bq[4];
  #pragma unroll
  for (int nt = 0; nt < 4; ++nt) bq[nt] = bias[c0 + (nt << 4) + m16];
  const float inv3 = 1.f / 3.f;
  #pragma unroll
  for (int t_i = 0; t_i < 2; ++t_i) {
    int mt = mt0 + t_i;
    if (mt < mtn) {
      #pragma unroll
      for (int nt = 0; nt < 4; ++nt) {
        floatx4 d = acc[t_i][nt];
        int cidx = c0 + (nt << 4) + m16;
        #pragma unroll
        for (int r = 0; r < 4; ++r) {
          int ii = (mt << 4) + (q << 2) + r;
          if (ii < n) xout[(size_t)(ob + ii) * C + cidx] = f2bf(d[r] * inv3 + bq[nt]);
        }
      }
    }
  }
  // zero pad rows [n, kext) of this cblk -- only the mg==0 block does it
  if (mg == 0) {
    for (int e = tid; e < ((kext - n) << 4); e += 256) {
      int row = n + (e >> 4);
      int c = c0 + ((e & 15) << 2);
      ushort4 z4; z4.x = z4.y = z4.z = z4.w = 0;
      *(ushort4*)(xout + (size_t)(ob + row) * C + c) = z4;
    }
  }
}

// ===== merged readout + head MLP: block/graph, 512 threads =================
__global__ __launch_bounds__(512) void k_feat_head(
    const unsigned short* __restrict__ x2, const float* __restrict__ pad2,
    const int* __restrict__ off, const int* __restrict__ natoms,
    const float* __restrict__ sgx, const float* __restrict__ latx,
    const float* __restrict__ W1, const float* __restrict__ b1,
    const float* __restrict__ g1, const float* __restrict__ be1,
    const float* __restrict__ m1, const float* __restrict__ v1,
    const float* __restrict__ W2, const float* __restrict__ b2,
    const float* __restrict__ g2, const float* __restrict__ be2,
    const float* __restrict__ m2, const float* __restrict__ v2,
    const float* __restrict__ W3, const float* __restrict__ b3,
    float* __restrict__ out) {
  int b = blockIdx.x, tid = threadIdx.x;  // 512
  int wv8 = tid >> 6, lane = tid & 63;
  int n = natoms[b], ob = off[b];
  __shared__ float part[8][256];
  __shared__ float f[PIN];
  __shared__ float h1[P1];
  __shared__ float h2[P1];
  __shared__ float red[512];
  float a0 = 0.f, a1 = 0.f, a2 = 0.f, a3 = 0.f;
  for (int r = wv8; r < n; r += 8) {
    uint2 raw = *(const uint2*)(x2 + (size_t)(ob + r) * C2 + (lane << 2));
    unsigned short us[4];
    *(uint2*)us = raw;
    a0 += bf2f(us[0]); a1 += bf2f(us[1]); a2 += bf2f(us[2]); a3 += bf2f(us[3]);
  }
  {
    float4 p = make_float4(a0, a1, a2, a3);
    *(float4*)&part[wv8][lane << 2] = p;
  }
  __syncthreads();
  if (tid < 256) {
    float s = 0.f;
    #pragma unroll
    for (int w = 0; w < 8; ++w) s += part[w][tid];
    f[tid] = s + (float)(NMAX - n) * pad2[tid];
  } else if (tid < 320) {
    f[tid] = sgx[b * SGE + (tid - 256)];
  } else if (tid < 448) {
    f[tid] = latx[b * LATH + (tid - 320)];
  }
  __syncthreads();
  {
    int o = tid;
    float acc = b1[o];
    for (int k = 0; k < PIN; ++k) acc += f[k] * W1[k * P1 + o];
    acc = (acc - m1[o]) * g1[o] * rsqrtf(v1[o] + EPSB) + be1[o];
    h1[o] = acc >= 0.f ? acc : 0.2f * acc;
  }
  __syncthreads();
  {
    int o = tid;
    float acc = b2[o];
    for (int k = 0; k < P1; ++k) acc += h1[k] * W2[k * P1 + o];
    acc = (acc - m2[o]) * g2[o] * rsqrtf(v2[o] + EPSB) + be2[o];
    h2[o] = acc >= 0.f ? acc : 0.2f * acc;
  }
  __syncthreads();
  red[tid] = h2[tid] * W3[tid];
  __syncthreads();
  for (int s = 256; s > 0; s >>= 1) {
    if (tid < s) red[tid] += red[tid + s];
    __syncthreads();
  }
  if (tid == 0) out[b] = red[0] + b3[0];
}

extern "C" void kernel_launch(void* const* d_in, const int* in_sizes, int n_in,
                              void* d_out, int out_size, void* d_ws, size_t ws_size,
                              hipStream_t stream) {
  const int*   comp       = (const int*)d_in[0];
  const int*   sg         = (const int*)d_in[1];
  const float* lat        = (const float*)d_in[2];
  const int*   period_idx = (const int*)d_in[3];
  const int*   group_idx  = (const int*)d_in[4];
  const float* sg_emb     = (const float*)d_in[5];
  const float* lat_W1     = (const float*)d_in[6];
  const float* lat_b1     = (const float*)d_in[7];
  const float* lat_bn1_g  = (const float*)d_in[8];
  const float* lat_bn1_b  = (const float*)d_in[9];
  const float* lat_bn1_m  = (const float*)d_in[10];
  const float* lat_bn1_v  = (const float*)d_in[11];
  const float* lat_W2     = (const float*)d_in[12];
  const float* lat_b2     = (const float*)d_in[13];
  const float* lat_bn2_g  = (const float*)d_in[14];
  const float* lat_bn2_b  = (const float*)d_in[15];
  const float* lat_bn2_m  = (const float*)d_in[16];
  const float* lat_bn2_v  = (const float*)d_in[17];
  const float* z_emb      = (const float*)d_in[18];
  const float* period_t   = (const float*)d_in[19];
  const float* group_t    = (const float*)d_in[20];
  const float* props      = (const float*)d_in[21];
  const float* W_props    = (const float*)d_in[22];
  const float* b_props    = (const float*)d_in[23];
  const float* W_phys     = (const float*)d_in[24];
  const float* b_phys     = (const float*)d_in[25];
  const float* gat1_W     = (const float*)d_in[26];
  const float* gat1_as    = (const float*)d_in[27];
  const float* gat1_ad    = (const float*)d_in[28];
  const float* gat1_b     = (const float*)d_in[29];
  const float* gat2_W     = (const float*)d_in[30];
  const float* gat2_as    = (const float*)d_in[31];
  const float* gat2_ad    = (const float*)d_in[32];
  const float* gat2_b     = (const float*)d_in[33];
  const float* pW1        = (const float*)d_in[34];
  const float* pb1        = (const float*)d_in[35];
  const float* pbn1_g     = (const float*)d_in[36];
  const float* pbn1_b     = (const float*)d_in[37];
  const float* pbn1_m     = (const float*)d_in[38];
  const float* pbn1_v     = (const float*)d_in[39];
  const float* pW2        = (const float*)d_in[40];
  const float* pb2        = (const float*)d_in[41];
  const float* pbn2_g     = (const float*)d_in[42];
  const float* pbn2_b     = (const float*)d_in[43];
  const float* pbn2_m     = (const float*)d_in[44];
  const float* pbn2_v     = (const float*)d_in[45];
  const float* pW3        = (const float*)d_in[46];
  const float* pb3        = (const float*)d_in[47];

  float* ws = (float*)d_ws;
  const size_t o_sgx  = 0;
  const size_t o_latx = o_sgx  + (size_t)BB * SGE;
  const size_t o_nat  = o_latx + (size_t)BB * LATH;
  const size_t o_off  = o_nat  + BB;
  const size_t o_aoff = o_off  + BB;
  const size_t o_meta = o_aoff + BB;
  const size_t o_z    = o_meta + 64;
  const size_t o_phys = o_z    + (size_t)BB * NMAX;
  const size_t o_wsv1 = o_phys + (size_t)NEL * 256;
  const size_t o_wdv1 = o_wsv1 + (size_t)C1 * 3;
  const size_t o_wsv2 = o_wdv1 + (size_t)C1 * 3;
  const size_t o_wdv2 = o_wsv2 + (size_t)C1 * 3;
  const size_t o_asrc = o_wdv2 + (size_t)C1 * 3;
  const size_t o_adst = o_asrc + (size_t)BB * NMAX * 3;
  const size_t o_pad2 = o_adst + (size_t)BB * NMAX * 3;
  const size_t o_zero = o_pad2 + 256;
  const size_t o_wt1  = o_zero + 256;
  const size_t o_wt2  = o_wt1  + (size_t)(3 * C1) * PIN / 2;
  const size_t o_x0   = o_wt2  + (size_t)(3 * C2) * C1 / 2;
  const size_t o_x1   = o_x0   + (size_t)XROWCAP * PIN / 2;  // 9.86M floats
  const size_t o_alph = o_x1   + (size_t)XROWCAP * PIN / 2;
  const size_t o_xwt  = o_alph + 9500000;                    // alpha ~35.4 MB actual
  // xwT chunk: 384 rows x XROWCAP shorts = 33.8 MB -> total ws ~155 MB

  float* sgx    = ws + o_sgx;
  float* latx   = ws + o_latx;
  int*   natoms = (int*)(ws + o_nat);
  int*   off    = (int*)(ws + o_off);
  int*   aoff   = (int*)(ws + o_aoff);
  int*   meta   = (int*)(ws + o_meta);
  int*   z      = (int*)(ws + o_z);
  float* physpe = ws + o_phys;
  float* wsv1   = ws + o_wsv1;
  float* wdv1   = ws + o_wdv1;
  float* wsv2   = ws + o_wsv2;
  float* wdv2   = ws + o_wdv2;
  float* asrc   = ws + o_asrc;
  float* adst   = ws + o_adst;
  float* pad2   = ws + o_pad2;
  float* zerobuf = ws + o_zero;
  unsigned short* wt1   = (unsigned short*)(ws + o_wt1);
  unsigned short* wt2   = (unsigned short*)(ws + o_wt2);
  unsigned short* x0    = (unsigned short*)(ws + o_x0);
  unsigned short* x1    = (unsigned short*)(ws + o_x1);
  unsigned short* x2    = x0;
  unsigned short* xwT   = (unsigned short*)(ws + o_xwt);
  unsigned short* alpha = (unsigned short*)(ws + o_alph);

  const int ALG = BB * 3 * MTMAX;

  k_setup<<<SETUP_GRID, 256, 0, stream>>>(
      comp, sg, lat, sg_emb,
      lat_W1, lat_b1, lat_bn1_g, lat_bn1_b, lat_bn1_m, lat_bn1_v,
      lat_W2, lat_b2, lat_bn2_g, lat_bn2_b, lat_bn2_m, lat_bn2_v,
      period_idx, group_idx, z_emb, period_t, group_t, props,
      W_props, b_props, W_phys, b_phys,
      gat1_W, gat1_as, gat1_ad, gat1_b,
      gat2_W, gat2_as, gat2_ad, gat2_b,
      sgx, latx, z, natoms, off, aoff, meta, zerobuf, physpe,
      wt1, wt2, wsv1, wdv1, wsv2, wdv2, pad2);

  k_nodep<<<BB, 256, 0, stream>>>(z, off, natoms, physpe, latx, sgx, x0);

  // ---- GAT layer 1 (C1=448 -> 7 cblks in chunks of 2,2,2,1) ----
  k_av2<<<1024, 256, 0, stream>>>(x0, wsv1, wdv1, off, natoms, asrc, adst, PIN);
  k_alpha<<<ALG, 256, 0, stream>>>(asrc, adst, off, natoms, aoff, alpha);
  {
    const int cbs[4] = {0, 2, 4, 6};
    const int ncbs[4] = {2, 2, 2, 1};
    for (int c = 0; c < 4; ++c) {
      k_gemm<<<GJT * 3 * ncbs[c], 256, 0, stream>>>(x0, wt1, meta, zerobuf,
          xwT, C1, cbs[c], ncbs[c]);
      k_phaseB<<<ncbs[c] * NMT * BB, 256, 0, stream>>>(xwT, alpha, aoff, off,
          natoms, meta, gat1_b, x1, C1, cbs[c], ncbs[c]);
    }
  }

  // ---- GAT layer 2 (C2=256 -> 4 cblks in chunks of 2,2) ----
  k_av2<<<1024, 256, 0, stream>>>(x1, wsv2, wdv2, off, natoms, asrc, adst, C1);
  k_alpha<<<ALG, 256, 0, stream>>>(asrc, adst, off, natoms, aoff, alpha);
  for (int c = 0; c < 2; ++c) {
    k_gemm<<<GJT * 6, 256, 0, stream>>>(x1, wt2, meta, zerobuf,
        xwT, C2, c * 2, 2);
    k_phaseB<<<2 * NMT * BB, 256, 0, stream>>>(xwT, alpha, aoff, off, natoms,
        meta, gat2_b, x2, C2, c * 2, 2);
  }

  // ---- merged readout + head ----
  k_feat_head<<<BB, 512, 0, stream>>>(x2, pad2, off, natoms, sgx, latx,
      pW1, pb1, pbn1_g, pbn1_b, pbn1_m, pbn1_v,
      pW2, pb2, pbn2_g, pbn2_b, pbn2_m, pbn2_v,
      pW3, pb3, (float*)d_out);
}

// Round 7
// 895.424 us; speedup vs baseline: 1.1256x; 1.0731x over previous
//
#include <hip/hip_runtime.h>
#include <math.h>

#define BB 256
#define NEL 90
#define NMAX 270
#define C1 448
#define C2 256
#define PIN 448
#define LATH 128
#define SGE 64
#define P1 512
#define EPSB 1e-5f

#define XROWCAP 44032           /* row capacity of x/xwT buffers (total32 ~38.6k fixed-seed) */
#define GJT (XROWCAP / 128)     /* 344 GEMM j-tiles */

typedef short shortx8 __attribute__((ext_vector_type(8)));
typedef float floatx4 __attribute__((ext_vector_type(4)));

__device__ __forceinline__ float bf2f(unsigned short u) {
  return __uint_as_float(((unsigned)u) << 16);
}
__device__ __forceinline__ unsigned short f2bf(float f) {
  unsigned x = __float_as_uint(f);
  unsigned r = (x + 0x7fffu + ((x >> 16) & 1u)) >> 16;
  return (unsigned short)r;
}
// async 16B global->LDS (gfx950). LDS dest: wave-uniform base + lane*16.
__device__ __forceinline__ void gld16(const void* g, void* l) {
  __builtin_amdgcn_global_load_lds(
      (const __attribute__((address_space(1))) unsigned int*)g,
      (__attribute__((address_space(3))) unsigned int*)l, 16, 0, 0);
}

// ================= mega prologue: prep | scan | physpe | wprep x2 | fold x2 | pad
#define NB_PREP  BB
#define NB_SCAN  1
#define NB_PHYS  NEL
#define NB_WP1   (14 * 42)
#define NB_WP2   (14 * 24)
#define NB_FOLD  112
#define NB_PAD   64
#define SETUP_GRID (NB_PREP + NB_SCAN + NB_PHYS + NB_WP1 + NB_WP2 + 2 * NB_FOLD + NB_PAD)

__global__ __launch_bounds__(256) void k_setup(
    const int* __restrict__ comp, const int* __restrict__ sg, const float* __restrict__ lat,
    const float* __restrict__ sg_emb,
    const float* __restrict__ lW1, const float* __restrict__ lb1,
    const float* __restrict__ lg1, const float* __restrict__ lbe1,
    const float* __restrict__ lm1, const float* __restrict__ lv1,
    const float* __restrict__ lW2, const float* __restrict__ lb2,
    const float* __restrict__ lg2, const float* __restrict__ lbe2,
    const float* __restrict__ lm2, const float* __restrict__ lv2,
    const int* __restrict__ period_idx, const int* __restrict__ group_idx,
    const float* __restrict__ z_emb, const float* __restrict__ period_t,
    const float* __restrict__ group_t, const float* __restrict__ props,
    const float* __restrict__ Wp, const float* __restrict__ bp,
    const float* __restrict__ Wphys, const float* __restrict__ bphys,
    const float* __restrict__ gat1_W, const float* __restrict__ gat1_as,
    const float* __restrict__ gat1_ad, const float* __restrict__ gat1_b,
    const float* __restrict__ gat2_W, const float* __restrict__ gat2_as,
    const float* __restrict__ gat2_ad, const float* __restrict__ gat2_b,
    float* __restrict__ sgx, float* __restrict__ latx, int* __restrict__ z,
    int* __restrict__ natoms, int* __restrict__ off, int* __restrict__ aoff,
    int* __restrict__ meta,
    float* __restrict__ zerobuf, float* __restrict__ physpe,
    unsigned short* __restrict__ wt1, unsigned short* __restrict__ wt2,
    float* __restrict__ wsv1, float* __restrict__ wdv1,
    float* __restrict__ wsv2, float* __restrict__ wdv2, float* __restrict__ pad2) {
  int r = blockIdx.x;
  int tid = threadIdx.x;
  int wv = tid >> 6, lane = tid & 63;

  if (r < NB_PREP) {  // ---- prep (z, sgx, latx) ----
    int b = r;
    __shared__ int cum[NEL];
    __shared__ float hbuf[LATH];
    __shared__ float latl[6];
    if (tid == 0) {
      int s = 0;
      for (int e = 0; e < NEL; ++e) { s += comp[b * NEL + e]; cum[e] = s; }
    }
    if (tid < 6) latl[tid] = lat[b * 6 + tid];
    __syncthreads();
    int n = cum[NEL - 1];
    for (int t = tid; t < NMAX; t += 256) {
      int zz = -1;
      if (t < n) {
        for (int e = 0; e < NEL; ++e) { if (cum[e] > t) { zz = e; break; } }
      }
      z[b * NMAX + t] = zz;
    }
    if (tid < SGE) sgx[b * SGE + tid] = sg_emb[sg[b] * SGE + tid];
    if (tid < LATH) {
      float acc = lb1[tid];
      for (int k = 0; k < 6; ++k) acc += latl[k] * lW1[k * LATH + tid];
      acc = (acc - lm1[tid]) * lg1[tid] * rsqrtf(lv1[tid] + EPSB) + lbe1[tid];
      hbuf[tid] = acc;
    }
    __syncthreads();
    if (tid < LATH) {
      float acc = lb2[tid];
      for (int k = 0; k < LATH; ++k) acc += hbuf[k] * lW2[k * LATH + tid];
      acc = (acc - lm2[tid]) * lg2[tid] * rsqrtf(lv2[tid] + EPSB) + lbe2[tid];
      latx[b * LATH + tid] = acc;
    }
    return;
  }
  r -= NB_PREP;
  if (r < NB_SCAN) {  // ---- scans (natoms, off32 kext-padded, aoff) + zero page
    __shared__ int sh[BB];
    zerobuf[tid] = 0.f;
    int v0 = 0;
    for (int e = 0; e < NEL; ++e) v0 += comp[tid * NEL + e];
    natoms[tid] = v0;
    int kx = ((v0 + 31) >> 5) << 5;   // kext-aligned row window per graph
    sh[tid] = kx;
    for (int d = 1; d < BB; d <<= 1) {
      __syncthreads();
      int v = (tid >= d) ? sh[tid - d] : 0;
      __syncthreads();
      sh[tid] += v;
    }
    __syncthreads();
    off[tid] = sh[tid] - kx;
    if (tid == BB - 1) meta[0] = sh[tid];   // total32 = padded row count
    __syncthreads();
    int sz = 3 * ((((v0 + 15) >> 4) << 4)) * ((((v0 + 31) >> 5) << 5));
    sh[tid] = sz;
    for (int d = 1; d < BB; d <<= 1) {
      __syncthreads();
      int v = (tid >= d) ? sh[tid - d] : 0;
      __syncthreads();
      sh[tid] += v;
    }
    __syncthreads();
    aoff[tid] = sh[tid] - sz;
    return;
  }
  r -= NB_SCAN;
  if (r < NB_PHYS) {  // ---- physpe rows ----
    int e = r;
    __shared__ float ph[128];
    if (tid < 32) ph[tid] = z_emb[e * 32 + tid];
    else if (tid < 64) ph[tid] = period_t[period_idx[e] * 32 + tid - 32];
    else if (tid < 96) ph[tid] = group_t[group_idx[e] * 32 + tid - 64];
    else if (tid < 128) {
      int j = tid - 96;
      float acc = bp[j];
      for (int k = 0; k < 20; ++k) acc += props[e * 20 + k] * Wp[k * 32 + j];
      ph[tid] = acc;
    }
    __syncthreads();
    float acc = bphys[tid];
    for (int k = 0; k < 128; ++k) acc += ph[k] * Wphys[k * 256 + tid];
    physpe[e * 256 + tid] = acc;
    return;
  }
  r -= NB_PHYS;
  if (r < NB_WP1 + NB_WP2) {  // ---- W transpose to bf16 W^T ----
    const float* W;
    unsigned short* Wt;
    int NC3, bx, by;
    if (r < NB_WP1) { W = gat1_W; Wt = wt1; NC3 = 3 * C1; bx = r % 14; by = r / 14; }
    else { int r2 = r - NB_WP1; W = gat2_W; Wt = wt2; NC3 = 3 * C2; bx = r2 % 14; by = r2 / 14; }
    int k0 = bx << 5, c0 = by << 5;
    __shared__ float ts[32][33];
    int e4 = tid << 2;
    int kk = e4 >> 5, cc = e4 & 31;
    float4 v = *(const float4*)(W + (size_t)(k0 + kk) * NC3 + c0 + cc);
    ts[kk][cc] = v.x; ts[kk][cc + 1] = v.y; ts[kk][cc + 2] = v.z; ts[kk][cc + 3] = v.w;
    __syncthreads();
    int c2 = tid & 31, kg = tid >> 5;
    ushort4 u;
    u.x = f2bf(ts[kg * 4 + 0][c2]); u.y = f2bf(ts[kg * 4 + 1][c2]);
    u.z = f2bf(ts[kg * 4 + 2][c2]); u.w = f2bf(ts[kg * 4 + 3][c2]);
    *(ushort4*)(Wt + (size_t)(c0 + c2) * 448 + k0 + (kg << 2)) = u;
    return;
  }
  r -= NB_WP1 + NB_WP2;
  if (r < 2 * NB_FOLD) {  // ---- fold a_s/a_d through W ----
    const float* W; const float* as_; const float* ad_;
    float* wsv; float* wdv; int NC3, C, kb;
    if (r < NB_FOLD) { W = gat1_W; as_ = gat1_as; ad_ = gat1_ad; wsv = wsv1; wdv = wdv1; NC3 = 3 * C1; C = C1; kb = r << 2; }
    else { int r2 = r - NB_FOLD; W = gat2_W; as_ = gat2_as; ad_ = gat2_ad; wsv = wsv2; wdv = wdv2; NC3 = 3 * C2; C = C2; kb = r2 << 2; }
    int k = kb + wv;
    for (int h = 0; h < 3; ++h) {
      float ss = 0.f, sd = 0.f;
      for (int c = lane; c < C; c += 64) {
        float wvv = W[(size_t)k * NC3 + h * C + c];
        ss += wvv * as_[h * C + c];
        sd += wvv * ad_[h * C + c];
      }
      for (int o = 32; o > 0; o >>= 1) { ss += __shfl_xor(ss, o); sd += __shfl_xor(sd, o); }
      if (lane == 0) { wsv[k * 3 + h] = ss; wdv[k * 3 + h] = sd; }
    }
    return;
  }
  r -= 2 * NB_FOLD;
  {  // ---- pad-row value after layer 2 ----
    int c = (r << 2) + wv;
    float s = 0.f;
    for (int k = lane; k < C1; k += 64) {
      const float* wr = gat2_W + (size_t)k * (3 * C2) + c;
      s += gat1_b[k] * (wr[0] + wr[C2] + wr[2 * C2]);
    }
    for (int o = 32; o > 0; o >>= 1) s += __shfl_xor(s, o);
    if (lane == 0) pad2[c] = s * (1.f / 3.f) + gat2_b[c];
  }
}

// ---------------- packed node features x0 [total32,448] bf16 + zero pads ---
__global__ __launch_bounds__(256) void k_nodep(
    const int* __restrict__ z, const int* __restrict__ off, const int* __restrict__ natoms,
    const float* __restrict__ physpe, const float* __restrict__ latx,
    const float* __restrict__ sgx, unsigned short* __restrict__ x0) {
  int b = blockIdx.x;
  int n = natoms[b], ob = off[b];
  int tid = threadIdx.x;
  __shared__ int zl[NMAX];
  for (int t = tid; t < n; t += 256) zl[t] = z[b * NMAX + t];
  __syncthreads();
  int items = n * 56;
  for (int e = tid; e < items; e += 256) {
    int t = e / 56, c8 = (e - t * 56) << 3;
    int zt = zl[t];
    float v[8];
    if (c8 < 256) {
      float4 a = *(const float4*)(physpe + zt * 256 + c8);
      float4 c = *(const float4*)(physpe + zt * 256 + c8 + 4);
      v[0] = a.x; v[1] = a.y; v[2] = a.z; v[3] = a.w;
      v[4] = c.x; v[5] = c.y; v[6] = c.z; v[7] = c.w;
    } else if (c8 < 384) {
      float4 a = *(const float4*)(latx + b * LATH + c8 - 256);
      float4 c = *(const float4*)(latx + b * LATH + c8 - 252);
      v[0] = a.x; v[1] = a.y; v[2] = a.z; v[3] = a.w;
      v[4] = c.x; v[5] = c.y; v[6] = c.z; v[7] = c.w;
    } else {
      float4 a = *(const float4*)(sgx + b * SGE + c8 - 384);
      float4 c = *(const float4*)(sgx + b * SGE + c8 - 380);
      v[0] = a.x; v[1] = a.y; v[2] = a.z; v[3] = a.w;
      v[4] = c.x; v[5] = c.y; v[6] = c.z; v[7] = c.w;
    }
    unsigned short u[8];
    #pragma unroll
    for (int i = 0; i < 8; ++i) u[i] = f2bf(v[i]);
    *(uint4*)(x0 + (size_t)(ob + t) * PIN + c8) = *(uint4*)u;
  }
  // zero pad rows [n, kext) so GEMM's XW of pad rows is defined (NaN-safe)
  int kext = ((n + 31) >> 5) << 5;
  int pitems = (kext - n) * 56;
  for (int e = tid; e < pitems; e += 256) {
    int rr = e / 56, c8 = (e - rr * 56) << 3;
    uint4 z4; z4.x = z4.y = z4.z = z4.w = 0u;
    *(uint4*)(x0 + (size_t)(ob + n + rr) * PIN + c8) = z4;
  }
}

// ---------------- asrc/adst: one WAVE per row (coalesced) ----------------
__global__ __launch_bounds__(256) void k_av2(
    const unsigned short* __restrict__ x, const float* __restrict__ wsv,
    const float* __restrict__ wdv, const int* __restrict__ off,
    const int* __restrict__ natoms, float* __restrict__ asrc,
    float* __restrict__ adst, int K) {
  __shared__ float sw[C1 * 3], dw[C1 * 3];
  int tid = threadIdx.x;
  for (int e = tid; e < K * 3; e += 256) { sw[e] = wsv[e]; dw[e] = wdv[e]; }
  __syncthreads();
  int total = off[BB - 1] + natoms[BB - 1];
  int wv = tid >> 6, lane = tid & 63;
  int nk8 = K >> 3;
  int stride = gridDim.x << 2;
  for (int row = (blockIdx.x << 2) + wv; row < total; row += stride) {
    float s0 = 0.f, s1 = 0.f, s2 = 0.f, d0 = 0.f, d1 = 0.f, d2 = 0.f;
    if (lane < nk8) {
      uint4 raw = *(const uint4*)(x + (size_t)row * K + (lane << 3));
      unsigned short us[8];
      *(uint4*)us = raw;
      #pragma unroll
      for (int u = 0; u < 8; ++u) {
        float xv = bf2f(us[u]);
        int kb = ((lane << 3) + u) * 3;
        s0 += xv * sw[kb + 0]; s1 += xv * sw[kb + 1]; s2 += xv * sw[kb + 2];
        d0 += xv * dw[kb + 0]; d1 += xv * dw[kb + 1]; d2 += xv * dw[kb + 2];
      }
    }
    #pragma unroll
    for (int o = 32; o > 0; o >>= 1) {
      s0 += __shfl_xor(s0, o); s1 += __shfl_xor(s1, o); s2 += __shfl_xor(s2, o);
      d0 += __shfl_xor(d0, o); d1 += __shfl_xor(d1, o); d2 += __shfl_xor(d2, o);
    }
    if (lane == 0) {
      asrc[row * 3 + 0] = s0; asrc[row * 3 + 1] = s1; asrc[row * 3 + 2] = s2;
      adst[row * 3 + 0] = d0; adst[row * 3 + 1] = d1; adst[row * 3 + 2] = d2;
    }
  }
}

// ---------------- alpha materialization (sharded): one (b,h,mtile)/block ---
#define MTMAX 17
__global__ __launch_bounds__(256) void k_alpha(
    const float* __restrict__ asrc, const float* __restrict__ adst,
    const int* __restrict__ off, const int* __restrict__ natoms,
    const int* __restrict__ aoff, unsigned short* __restrict__ alpha) {
  int bid = blockIdx.x;
  int b = bid & (BB - 1);
  int hm = bid >> 8;
  int h = hm % 3;
  int mt = hm / 3;
  int n = natoms[b];
  if (n == 0) return;
  int mtn = (n + 15) >> 4;
  if (mt >= mtn) return;
  int ktn = (n + 31) >> 5;
  int rext = mtn << 4, kext = ktn << 5;
  int ob = off[b];
  size_t ab = (size_t)aoff[b] + (size_t)h * rext * kext;
  int tid = threadIdx.x;
  int wv = tid >> 6, lane = tid & 63;
  __shared__ float asl[288];
  for (int j = tid; j < kext; j += 256)
    asl[j] = (j < n) ? asrc[(ob + j) * 3 + h] : 0.f;
  __syncthreads();
  #pragma unroll
  for (int r = 0; r < 4; ++r) {
    int i = (mt << 4) + (wv << 2) + r;
    unsigned short* rowp = alpha + ab + (size_t)i * kext;
    if (i >= n) {
      for (int j = lane; j < kext; j += 64) rowp[j] = 0;
      continue;
    }
    float ad = adst[(ob + i) * 3 + h];
    float m = -1e30f;
    for (int j = lane; j < n; j += 64) {
      float sc = asl[j] + ad;
      sc = fmaxf(sc, 0.2f * sc);
      m = fmaxf(m, sc);
    }
    for (int o = 32; o > 0; o >>= 1) m = fmaxf(m, __shfl_xor(m, o));
    float s = 0.f;
    for (int j = lane; j < n; j += 64) {
      float sc = asl[j] + ad;
      sc = fmaxf(sc, 0.2f * sc);
      s += __expf(sc - m);
    }
    for (int o = 32; o > 0; o >>= 1) s += __shfl_xor(s, o);
    float rs = 1.f / s;
    for (int j = lane; j < kext; j += 64) {
      float v = 0.f;
      if (j < n) {
        float sc = asl[j] + ad;
        sc = fmaxf(sc, 0.2f * sc);
        v = __expf(sc - m) * rs;
      }
      rowp[j] = f2bf(v);
    }
  }
}

// ---------------- chunked dense GEMM: xwT rows = chunk cols, transposed ----
// R7: templated BN = 64*NCB. For NCB=2 one block computes all 128 contiguous
// cols of a head (Wt rows and xwT bands adjacent by construction):
// 16 MFMA/wave/k-step (2x R6) and X re-read 3x/launch instead of 6x.
// BM=128 BK=32, gld16 dbuf, XOR-swizzled chunks (both-sides involution).
// Epilogue: transpose through LDS in NCB passes of 64 c-rows, coalesced
// 64-B row writes (no partial-line RMW).
template <int NCB>
__global__ __launch_bounds__(256, 4) void k_gemm(
    const unsigned short* __restrict__ X, const unsigned short* __restrict__ W,
    const int* __restrict__ meta, const float* __restrict__ zerobuf,
    unsigned short* __restrict__ xwT, int C, int cb0) {
  int total = meta[0];
  int mb = blockIdx.x / 3;
  int m0 = mb << 7;
  if (m0 >= total) return;
  int h = blockIdx.x - mb * 3;
  int colbase = h * C + (cb0 << 6);       // row base in Wt (NCB*64 rows)
  int bandbase = h * (NCB << 6);          // row base in xwT chunk
  int tid = threadIdx.x;
  int wv = tid >> 6, lane = tid & 63;
  int m16 = lane & 15, q = lane >> 4;

  // LDS: As 2x4096 shorts, Bs 2x(2048*NCB) shorts. Epilogue reuses smem as
  // a 64x132 transpose buffer per pass (8448 shorts <= 16384).
  __shared__ unsigned short smem[8192 + 4096 * NCB];
  unsigned short* As0 = smem;
  unsigned short* As1 = smem + 4096;
  unsigned short* Bs0 = smem + 8192;
  unsigned short* Bs1 = smem + 8192 + 2048 * NCB;

  int l4 = lane >> 2, ci = lane & 3;
  int ra0 = (wv << 4) + l4;
  int ra1 = ra0 + 64;
  int rb  = (wv << 4) + l4;
  // pre-swizzled global sources (LDS dest linear; read applies same XOR)
  const unsigned short* asrc0 = (m0 + ra0 < total)
      ? (X + (size_t)(m0 + ra0) * 448 + ((ci ^ (ra0 & 3)) << 3))
      : (const unsigned short*)zerobuf;
  const unsigned short* asrc1 = (m0 + ra1 < total)
      ? (X + (size_t)(m0 + ra1) * 448 + ((ci ^ (ra1 & 3)) << 3))
      : (const unsigned short*)zerobuf;
  const unsigned short* bsrc = W + (size_t)(colbase + rb) * 448 + ((ci ^ (rb & 3)) << 3);
  // rows rb+64 (NCB==2): (rb+64)&3 == rb&3 -> same swizzle, source +64*448

  floatx4 acc[2][4 * NCB];
  #pragma unroll
  for (int ti = 0; ti < 2; ++ti)
    #pragma unroll
    for (int nt = 0; nt < 4 * NCB; ++nt) acc[ti][nt] = (floatx4)0.f;

  gld16(asrc0, As0 + (wv << 9));
  gld16(asrc1, As0 + 2048 + (wv << 9));
  gld16(bsrc, Bs0 + (wv << 9));
  if constexpr (NCB == 2) gld16(bsrc + (size_t)64 * 448, Bs0 + 2048 + (wv << 9));
  __syncthreads();

  #pragma unroll 2
  for (int s = 0; s < 14; ++s) {
    int cur = s & 1;
    unsigned short* Ab = cur ? As1 : As0;
    unsigned short* Bb = cur ? Bs1 : Bs0;
    if (s < 13) {
      int k1 = (s + 1) << 5;
      unsigned short* An = cur ? As0 : As1;
      unsigned short* Bn = cur ? Bs0 : Bs1;
      gld16(asrc0 + k1, An + (wv << 9));
      gld16(asrc1 + k1, An + 2048 + (wv << 9));
      gld16(bsrc + k1, Bn + (wv << 9));
      if constexpr (NCB == 2) gld16(bsrc + (size_t)64 * 448 + k1, Bn + 2048 + (wv << 9));
    }
    shortx8 bfr[4 * NCB];
    #pragma unroll
    for (int nt = 0; nt < 4 * NCB; ++nt) {
      int rr = (nt << 4) + m16;
      bfr[nt] = *(const shortx8*)(Bb + rr * 32 + ((q ^ (rr & 3)) << 3));
    }
    #pragma unroll
    for (int ti = 0; ti < 2; ++ti) {
      int ra = ((((wv << 1) + ti) << 4) + m16);
      shortx8 a = *(const shortx8*)(Ab + ra * 32 + ((q ^ (ra & 3)) << 3));
      #pragma unroll
      for (int nt = 0; nt < 4 * NCB; ++nt)
        acc[ti][nt] = __builtin_amdgcn_mfma_f32_16x16x32_bf16(a, bfr[nt], acc[ti][nt], 0, 0, 0);
    }
    __syncthreads();
  }

  // epilogue: NCB passes of 64 c-rows through LDS, coalesced row writes
  unsigned short* tb_ = smem;  // 64 x 132 shorts per pass
  #pragma unroll
  for (int pass = 0; pass < NCB; ++pass) {
    __syncthreads();
    #pragma unroll
    for (int ti = 0; ti < 2; ++ti) {
      int j0 = (((wv << 1) + ti) << 4) + (q << 2);
      #pragma unroll
      for (int ntl = 0; ntl < 4; ++ntl) {
        int c = (ntl << 4) + m16;
        floatx4 d = acc[ti][(pass << 2) + ntl];
        ushort4 u;
        u.x = f2bf(d[0]); u.y = f2bf(d[1]); u.z = f2bf(d[2]); u.w = f2bf(d[3]);
        *(ushort4*)(tb_ + c * 132 + j0) = u;
      }
    }
    __syncthreads();
    {
      int c = tid >> 2, js = (tid & 3) << 5;
      int jglob = m0 + js;
      if (jglob < total) {  // total, js 32-aligned -> whole run valid
        unsigned short* dst = xwT + (size_t)(bandbase + (pass << 6) + c) * total + jglob;
        const unsigned short* src = tb_ + c * 132 + js;
        *(uint4*)(dst)      = *(const uint4*)(src);
        *(uint4*)(dst + 8)  = *(const uint4*)(src + 8);
        *(uint4*)(dst + 16) = *(const uint4*)(src + 16);
        *(uint4*)(dst + 24) = *(const uint4*)(src + 24);
      }
    }
  }
}

// ---------------- chunked phase B: out += mean_h(alpha_h @ XW_h) + bias ----
// R7: #pragma unroll 4 on the k-loop -- R6 showed per-wave load-latency
// chains limit BW to 770 GB/s (unroll 2 => ~12 loads in flight). 4
// iterations' 24 loads are address-independent -> compiler hoists into one
// issue burst. No LDS, no barriers.
#define NMT 3
__global__ __launch_bounds__(256, 4) void k_phaseB(
    const unsigned short* __restrict__ xwT, const unsigned short* __restrict__ alpha,
    const int* __restrict__ aoff, const int* __restrict__ off,
    const int* __restrict__ natoms, const int* __restrict__ meta,
    const float* __restrict__ bias, unsigned short* __restrict__ xout,
    int C, int cb0, int ncb) {
  int pitch = meta[0];
  int bid = blockIdx.x;
  int b = bid & (BB - 1);
  int g = bid >> 8;
  int i = g / NMT;
  int mg = g - i * NMT;
  int c0 = (cb0 + i) << 6;
  int n = natoms[b];
  if (n == 0) return;
  int mtn = (n + 15) >> 4;
  if ((mg << 3) >= mtn) return;   // whole block's mt range empty
  int ob = off[b];
  size_t ab = (size_t)aoff[b];
  int tid = threadIdx.x;
  int wv = tid >> 6, lane = tid & 63;
  int m16 = lane & 15, q = lane >> 4;
  int jmax = mtn << 4;
  int ktn = (n + 31) >> 5;
  int kext = ktn << 5;
  size_t hstride = (size_t)jmax * kext;

  int mt0 = (mg << 3) + (wv << 1);   // this wave: mt0, mt0+1 (covers 0..23)
  bool act0 = mt0 < mtn;
  bool act1 = mt0 + 1 < mtn;

  floatx4 acc[2][4];
  #pragma unroll
  for (int t_i = 0; t_i < 2; ++t_i)
    #pragma unroll
    for (int nt = 0; nt < 4; ++nt) acc[t_i][nt] = (floatx4)0.f;

  if (act0) {
    for (int h = 0; h < 3; ++h) {
      const unsigned short* ap = alpha + ab + (size_t)h * hstride + (q << 3);
      const unsigned short* xb = xwT + (size_t)(((h * ncb + i) << 6) + m16) * pitch + ob + (q << 3);
      #pragma unroll 4
      for (int k0p = 0; k0p < kext; k0p += 32) {
        shortx8 tb[4];
        #pragma unroll
        for (int nt = 0; nt < 4; ++nt)
          tb[nt] = *(const shortx8*)(xb + (size_t)(nt << 4) * pitch + k0p);
        {
          shortx8 af = *(const shortx8*)(ap + (size_t)((mt0 << 4) + m16) * kext + k0p);
          #pragma unroll
          for (int nt = 0; nt < 4; ++nt)
            acc[0][nt] = __builtin_amdgcn_mfma_f32_16x16x32_bf16(af, tb[nt], acc[0][nt], 0, 0, 0);
        }
        if (act1) {
          shortx8 af = *(const shortx8*)(ap + (size_t)(((mt0 + 1) << 4) + m16) * kext + k0p);
          #pragma unroll
          for (int nt = 0; nt < 4; ++nt)
            acc[1][nt] = __builtin_amdgcn_mfma_f32_16x16x32_bf16(af, tb[nt], acc[1][nt], 0, 0, 0);
        }
      }
    }
  }
  float bq[4];
  #pragma unroll
  for (int nt = 0; nt < 4; ++nt) bq[nt] = bias[c0 + (nt << 4) + m16];
  const float inv3 = 1.f / 3.f;
  #pragma unroll
  for (int t_i = 0; t_i < 2; ++t_i) {
    int mt = mt0 + t_i;
    if (mt < mtn) {
      #pragma unroll
      for (int nt = 0; nt < 4; ++nt) {
        floatx4 d = acc[t_i][nt];
        int cidx = c0 + (nt << 4) + m16;
        #pragma unroll
        for (int r = 0; r < 4; ++r) {
          int ii = (mt << 4) + (q << 2) + r;
          if (ii < n) xout[(size_t)(ob + ii) * C + cidx] = f2bf(d[r] * inv3 + bq[nt]);
        }
      }
    }
  }
  // zero pad rows [n, kext) of this cblk -- only the mg==0 block does it
  if (mg == 0) {
    for (int e = tid; e < ((kext - n) << 4); e += 256) {
      int row = n + (e >> 4);
      int c = c0 + ((e & 15) << 2);
      ushort4 z4; z4.x = z4.y = z4.z = z4.w = 0;
      *(ushort4*)(xout + (size_t)(ob + row) * C + c) = z4;
    }
  }
}

// ===== merged readout + head MLP: block/graph, 512 threads =================
__global__ __launch_bounds__(512) void k_feat_head(
    const unsigned short* __restrict__ x2, const float* __restrict__ pad2,
    const int* __restrict__ off, const int* __restrict__ natoms,
    const float* __restrict__ sgx, const float* __restrict__ latx,
    const float* __restrict__ W1, const float* __restrict__ b1,
    const float* __restrict__ g1, const float* __restrict__ be1,
    const float* __restrict__ m1, const float* __restrict__ v1,
    const float* __restrict__ W2, const float* __restrict__ b2,
    const float* __restrict__ g2, const float* __restrict__ be2,
    const float* __restrict__ m2, const float* __restrict__ v2,
    const float* __restrict__ W3, const float* __restrict__ b3,
    float* __restrict__ out) {
  int b = blockIdx.x, tid = threadIdx.x;  // 512
  int wv8 = tid >> 6, lane = tid & 63;
  int n = natoms[b], ob = off[b];
  __shared__ float part[8][256];
  __shared__ float f[PIN];
  __shared__ float h1[P1];
  __shared__ float h2[P1];
  __shared__ float red[512];
  float a0 = 0.f, a1 = 0.f, a2 = 0.f, a3 = 0.f;
  for (int r = wv8; r < n; r += 8) {
    uint2 raw = *(const uint2*)(x2 + (size_t)(ob + r) * C2 + (lane << 2));
    unsigned short us[4];
    *(uint2*)us = raw;
    a0 += bf2f(us[0]); a1 += bf2f(us[1]); a2 += bf2f(us[2]); a3 += bf2f(us[3]);
  }
  {
    float4 p = make_float4(a0, a1, a2, a3);
    *(float4*)&part[wv8][lane << 2] = p;
  }
  __syncthreads();
  if (tid < 256) {
    float s = 0.f;
    #pragma unroll
    for (int w = 0; w < 8; ++w) s += part[w][tid];
    f[tid] = s + (float)(NMAX - n) * pad2[tid];
  } else if (tid < 320) {
    f[tid] = sgx[b * SGE + (tid - 256)];
  } else if (tid < 448) {
    f[tid] = latx[b * LATH + (tid - 320)];
  }
  __syncthreads();
  {
    int o = tid;
    float acc = b1[o];
    for (int k = 0; k < PIN; ++k) acc += f[k] * W1[k * P1 + o];
    acc = (acc - m1[o]) * g1[o] * rsqrtf(v1[o] + EPSB) + be1[o];
    h1[o] = acc >= 0.f ? acc : 0.2f * acc;
  }
  __syncthreads();
  {
    int o = tid;
    float acc = b2[o];
    for (int k = 0; k < P1; ++k) acc += h1[k] * W2[k * P1 + o];
    acc = (acc - m2[o]) * g2[o] * rsqrtf(v2[o] + EPSB) + be2[o];
    h2[o] = acc >= 0.f ? acc : 0.2f * acc;
  }
  __syncthreads();
  red[tid] = h2[tid] * W3[tid];
  __syncthreads();
  for (int s = 256; s > 0; s >>= 1) {
    if (tid < s) red[tid] += red[tid + s];
    __syncthreads();
  }
  if (tid == 0) out[b] = red[0] + b3[0];
}

extern "C" void kernel_launch(void* const* d_in, const int* in_sizes, int n_in,
                              void* d_out, int out_size, void* d_ws, size_t ws_size,
                              hipStream_t stream) {
  const int*   comp       = (const int*)d_in[0];
  const int*   sg         = (const int*)d_in[1];
  const float* lat        = (const float*)d_in[2];
  const int*   period_idx = (const int*)d_in[3];
  const int*   group_idx  = (const int*)d_in[4];
  const float* sg_emb     = (const float*)d_in[5];
  const float* lat_W1     = (const float*)d_in[6];
  const float* lat_b1     = (const float*)d_in[7];
  const float* lat_bn1_g  = (const float*)d_in[8];
  const float* lat_bn1_b  = (const float*)d_in[9];
  const float* lat_bn1_m  = (const float*)d_in[10];
  const float* lat_bn1_v  = (const float*)d_in[11];
  const float* lat_W2     = (const float*)d_in[12];
  const float* lat_b2     = (const float*)d_in[13];
  const float* lat_bn2_g  = (const float*)d_in[14];
  const float* lat_bn2_b  = (const float*)d_in[15];
  const float* lat_bn2_m  = (const float*)d_in[16];
  const float* lat_bn2_v  = (const float*)d_in[17];
  const float* z_emb      = (const float*)d_in[18];
  const float* period_t   = (const float*)d_in[19];
  const float* group_t    = (const float*)d_in[20];
  const float* props      = (const float*)d_in[21];
  const float* W_props    = (const float*)d_in[22];
  const float* b_props    = (const float*)d_in[23];
  const float* W_phys     = (const float*)d_in[24];
  const float* b_phys     = (const float*)d_in[25];
  const float* gat1_W     = (const float*)d_in[26];
  const float* gat1_as    = (const float*)d_in[27];
  const float* gat1_ad    = (const float*)d_in[28];
  const float* gat1_b     = (const float*)d_in[29];
  const float* gat2_W     = (const float*)d_in[30];
  const float* gat2_as    = (const float*)d_in[31];
  const float* gat2_ad    = (const float*)d_in[32];
  const float* gat2_b     = (const float*)d_in[33];
  const float* pW1        = (const float*)d_in[34];
  const float* pb1        = (const float*)d_in[35];
  const float* pbn1_g     = (const float*)d_in[36];
  const float* pbn1_b     = (const float*)d_in[37];
  const float* pbn1_m     = (const float*)d_in[38];
  const float* pbn1_v     = (const float*)d_in[39];
  const float* pW2        = (const float*)d_in[40];
  const float* pb2        = (const float*)d_in[41];
  const float* pbn2_g     = (const float*)d_in[42];
  const float* pbn2_b     = (const float*)d_in[43];
  const float* pbn2_m     = (const float*)d_in[44];
  const float* pbn2_v     = (const float*)d_in[45];
  const float* pW3        = (const float*)d_in[46];
  const float* pb3        = (const float*)d_in[47];

  float* ws = (float*)d_ws;
  const size_t o_sgx  = 0;
  const size_t o_latx = o_sgx  + (size_t)BB * SGE;
  const size_t o_nat  = o_latx + (size_t)BB * LATH;
  const size_t o_off  = o_nat  + BB;
  const size_t o_aoff = o_off  + BB;
  const size_t o_meta = o_aoff + BB;
  const size_t o_z    = o_meta + 64;
  const size_t o_phys = o_z    + (size_t)BB * NMAX;
  const size_t o_wsv1 = o_phys + (size_t)NEL * 256;
  const size_t o_wdv1 = o_wsv1 + (size_t)C1 * 3;
  const size_t o_wsv2 = o_wdv1 + (size_t)C1 * 3;
  const size_t o_wdv2 = o_wsv2 + (size_t)C1 * 3;
  const size_t o_asrc = o_wdv2 + (size_t)C1 * 3;
  const size_t o_adst = o_asrc + (size_t)BB * NMAX * 3;
  const size_t o_pad2 = o_adst + (size_t)BB * NMAX * 3;
  const size_t o_zero = o_pad2 + 256;
  const size_t o_wt1  = o_zero + 256;
  const size_t o_wt2  = o_wt1  + (size_t)(3 * C1) * PIN / 2;
  const size_t o_x0   = o_wt2  + (size_t)(3 * C2) * C1 / 2;
  const size_t o_x1   = o_x0   + (size_t)XROWCAP * PIN / 2;  // 9.86M floats
  const size_t o_alph = o_x1   + (size_t)XROWCAP * PIN / 2;
  const size_t o_xwt  = o_alph + 9500000;                    // alpha ~35.4 MB actual
  // xwT chunk: 384 rows x XROWCAP shorts = 33.8 MB -> total ws ~155 MB

  float* sgx    = ws + o_sgx;
  float* latx   = ws + o_latx;
  int*   natoms = (int*)(ws + o_nat);
  int*   off    = (int*)(ws + o_off);
  int*   aoff   = (int*)(ws + o_aoff);
  int*   meta   = (int*)(ws + o_meta);
  int*   z      = (int*)(ws + o_z);
  float* physpe = ws + o_phys;
  float* wsv1   = ws + o_wsv1;
  float* wdv1   = ws + o_wdv1;
  float* wsv2   = ws + o_wsv2;
  float* wdv2   = ws + o_wdv2;
  float* asrc   = ws + o_asrc;
  float* adst   = ws + o_adst;
  float* pad2   = ws + o_pad2;
  float* zerobuf = ws + o_zero;
  unsigned short* wt1   = (unsigned short*)(ws + o_wt1);
  unsigned short* wt2   = (unsigned short*)(ws + o_wt2);
  unsigned short* x0    = (unsigned short*)(ws + o_x0);
  unsigned short* x1    = (unsigned short*)(ws + o_x1);
  unsigned short* x2    = x0;
  unsigned short* xwT   = (unsigned short*)(ws + o_xwt);
  unsigned short* alpha = (unsigned short*)(ws + o_alph);

  const int ALG = BB * 3 * MTMAX;

  k_setup<<<SETUP_GRID, 256, 0, stream>>>(
      comp, sg, lat, sg_emb,
      lat_W1, lat_b1, lat_bn1_g, lat_bn1_b, lat_bn1_m, lat_bn1_v,
      lat_W2, lat_b2, lat_bn2_g, lat_bn2_b, lat_bn2_m, lat_bn2_v,
      period_idx, group_idx, z_emb, period_t, group_t, props,
      W_props, b_props, W_phys, b_phys,
      gat1_W, gat1_as, gat1_ad, gat1_b,
      gat2_W, gat2_as, gat2_ad, gat2_b,
      sgx, latx, z, natoms, off, aoff, meta, zerobuf, physpe,
      wt1, wt2, wsv1, wdv1, wsv2, wdv2, pad2);

  k_nodep<<<BB, 256, 0, stream>>>(z, off, natoms, physpe, latx, sgx, x0);

  // ---- GAT layer 1 (C1=448 -> 7 cblks in chunks of 2,2,2,1) ----
  k_av2<<<1024, 256, 0, stream>>>(x0, wsv1, wdv1, off, natoms, asrc, adst, PIN);
  k_alpha<<<ALG, 256, 0, stream>>>(asrc, adst, off, natoms, aoff, alpha);
  {
    const int cbs[4] = {0, 2, 4, 6};
    for (int c = 0; c < 3; ++c) {
      k_gemm<2><<<GJT * 3, 256, 0, stream>>>(x0, wt1, meta, zerobuf, xwT, C1, cbs[c]);
      k_phaseB<<<2 * NMT * BB, 256, 0, stream>>>(xwT, alpha, aoff, off,
          natoms, meta, gat1_b, x1, C1, cbs[c], 2);
    }
    k_gemm<1><<<GJT * 3, 256, 0, stream>>>(x0, wt1, meta, zerobuf, xwT, C1, 6);
    k_phaseB<<<1 * NMT * BB, 256, 0, stream>>>(xwT, alpha, aoff, off,
        natoms, meta, gat1_b, x1, C1, 6, 1);
  }

  // ---- GAT layer 2 (C2=256 -> 4 cblks in chunks of 2,2) ----
  k_av2<<<1024, 256, 0, stream>>>(x1, wsv2, wdv2, off, natoms, asrc, adst, C1);
  k_alpha<<<ALG, 256, 0, stream>>>(asrc, adst, off, natoms, aoff, alpha);
  for (int c = 0; c < 2; ++c) {
    k_gemm<2><<<GJT * 3, 256, 0, stream>>>(x1, wt2, meta, zerobuf, xwT, C2, c * 2);
    k_phaseB<<<2 * NMT * BB, 256, 0, stream>>>(xwT, alpha, aoff, off, natoms,
        meta, gat2_b, x2, C2, c * 2, 2);
  }

  // ---- merged readout + head ----
  k_feat_head<<<BB, 512, 0, stream>>>(x2, pad2, off, natoms, sgx, latx,
      pW1, pb1, pbn1_g, pbn1_b, pbn1_m, pbn1_v,
      pW2, pb2, pbn2_g, pbn2_b, pbn2_m, pbn2_v,
      pW3, pb3, (float*)d_out);
}

// Round 8
// 838.106 us; speedup vs baseline: 1.2026x; 1.0684x over previous
//
#include <hip/hip_runtime.h>
#include <math.h>

#define BB 256
#define NEL 90
#define NMAX 270
#define C1 448
#define C2 256
#define PIN 448
#define LATH 128
#define SGE 64
#define P1 512
#define EPSB 1e-5f

#define XROWCAP 44032           /* row capacity of x/xwT buffers (total32 ~38.6k fixed-seed) */
#define GJT (XROWCAP / 128)     /* 344 GEMM j-tiles */

typedef short shortx8 __attribute__((ext_vector_type(8)));
typedef float floatx4 __attribute__((ext_vector_type(4)));

__device__ __forceinline__ float bf2f(unsigned short u) {
  return __uint_as_float(((unsigned)u) << 16);
}
__device__ __forceinline__ unsigned short f2bf(float f) {
  unsigned x = __float_as_uint(f);
  unsigned r = (x + 0x7fffu + ((x >> 16) & 1u)) >> 16;
  return (unsigned short)r;
}
// async 16B global->LDS (gfx950). LDS dest: wave-uniform base + lane*16.
__device__ __forceinline__ void gld16(const void* g, void* l) {
  __builtin_amdgcn_global_load_lds(
      (const __attribute__((address_space(1))) unsigned int*)g,
      (__attribute__((address_space(3))) unsigned int*)l, 16, 0, 0);
}

// ================= mega prologue: prep | scan | physpe | wprep x2 | fold x2 | pad
#define NB_PREP  BB
#define NB_SCAN  1
#define NB_PHYS  NEL
#define NB_WP1   (14 * 42)
#define NB_WP2   (14 * 24)
#define NB_FOLD  112
#define NB_PAD   64
#define SETUP_GRID (NB_PREP + NB_SCAN + NB_PHYS + NB_WP1 + NB_WP2 + 2 * NB_FOLD + NB_PAD)

__global__ __launch_bounds__(256) void k_setup(
    const int* __restrict__ comp, const int* __restrict__ sg, const float* __restrict__ lat,
    const float* __restrict__ sg_emb,
    const float* __restrict__ lW1, const float* __restrict__ lb1,
    const float* __restrict__ lg1, const float* __restrict__ lbe1,
    const float* __restrict__ lm1, const float* __restrict__ lv1,
    const float* __restrict__ lW2, const float* __restrict__ lb2,
    const float* __restrict__ lg2, const float* __restrict__ lbe2,
    const float* __restrict__ lm2, const float* __restrict__ lv2,
    const int* __restrict__ period_idx, const int* __restrict__ group_idx,
    const float* __restrict__ z_emb, const float* __restrict__ period_t,
    const float* __restrict__ group_t, const float* __restrict__ props,
    const float* __restrict__ Wp, const float* __restrict__ bp,
    const float* __restrict__ Wphys, const float* __restrict__ bphys,
    const float* __restrict__ gat1_W, const float* __restrict__ gat1_as,
    const float* __restrict__ gat1_ad, const float* __restrict__ gat1_b,
    const float* __restrict__ gat2_W, const float* __restrict__ gat2_as,
    const float* __restrict__ gat2_ad, const float* __restrict__ gat2_b,
    float* __restrict__ sgx, float* __restrict__ latx, int* __restrict__ z,
    int* __restrict__ natoms, int* __restrict__ off, int* __restrict__ aoff,
    int* __restrict__ meta,
    float* __restrict__ zerobuf, float* __restrict__ physpe,
    unsigned short* __restrict__ wt1, unsigned short* __restrict__ wt2,
    float* __restrict__ wsv1, float* __restrict__ wdv1,
    float* __restrict__ wsv2, float* __restrict__ wdv2, float* __restrict__ pad2) {
  int r = blockIdx.x;
  int tid = threadIdx.x;
  int wv = tid >> 6, lane = tid & 63;

  if (r < NB_PREP) {  // ---- prep (z, sgx, latx) ----
    int b = r;
    __shared__ int cum[NEL];
    __shared__ float hbuf[LATH];
    __shared__ float latl[6];
    if (tid == 0) {
      int s = 0;
      for (int e = 0; e < NEL; ++e) { s += comp[b * NEL + e]; cum[e] = s; }
    }
    if (tid < 6) latl[tid] = lat[b * 6 + tid];
    __syncthreads();
    int n = cum[NEL - 1];
    for (int t = tid; t < NMAX; t += 256) {
      int zz = -1;
      if (t < n) {
        for (int e = 0; e < NEL; ++e) { if (cum[e] > t) { zz = e; break; } }
      }
      z[b * NMAX + t] = zz;
    }
    if (tid < SGE) sgx[b * SGE + tid] = sg_emb[sg[b] * SGE + tid];
    if (tid < LATH) {
      float acc = lb1[tid];
      for (int k = 0; k < 6; ++k) acc += latl[k] * lW1[k * LATH + tid];
      acc = (acc - lm1[tid]) * lg1[tid] * rsqrtf(lv1[tid] + EPSB) + lbe1[tid];
      hbuf[tid] = acc;
    }
    __syncthreads();
    if (tid < LATH) {
      float acc = lb2[tid];
      for (int k = 0; k < LATH; ++k) acc += hbuf[k] * lW2[k * LATH + tid];
      acc = (acc - lm2[tid]) * lg2[tid] * rsqrtf(lv2[tid] + EPSB) + lbe2[tid];
      latx[b * LATH + tid] = acc;
    }
    return;
  }
  r -= NB_PREP;
  if (r < NB_SCAN) {  // ---- scans (natoms, off32 kext-padded, aoff) + zero page
    __shared__ int sh[BB];
    zerobuf[tid] = 0.f;
    int v0 = 0;
    for (int e = 0; e < NEL; ++e) v0 += comp[tid * NEL + e];
    natoms[tid] = v0;
    int kx = ((v0 + 31) >> 5) << 5;   // kext-aligned row window per graph
    sh[tid] = kx;
    for (int d = 1; d < BB; d <<= 1) {
      __syncthreads();
      int v = (tid >= d) ? sh[tid - d] : 0;
      __syncthreads();
      sh[tid] += v;
    }
    __syncthreads();
    off[tid] = sh[tid] - kx;
    if (tid == BB - 1) meta[0] = sh[tid];   // total32 = padded row count
    __syncthreads();
    int sz = 3 * ((((v0 + 15) >> 4) << 4)) * ((((v0 + 31) >> 5) << 5));
    sh[tid] = sz;
    for (int d = 1; d < BB; d <<= 1) {
      __syncthreads();
      int v = (tid >= d) ? sh[tid - d] : 0;
      __syncthreads();
      sh[tid] += v;
    }
    __syncthreads();
    aoff[tid] = sh[tid] - sz;
    return;
  }
  r -= NB_SCAN;
  if (r < NB_PHYS) {  // ---- physpe rows ----
    int e = r;
    __shared__ float ph[128];
    if (tid < 32) ph[tid] = z_emb[e * 32 + tid];
    else if (tid < 64) ph[tid] = period_t[period_idx[e] * 32 + tid - 32];
    else if (tid < 96) ph[tid] = group_t[group_idx[e] * 32 + tid - 64];
    else if (tid < 128) {
      int j = tid - 96;
      float acc = bp[j];
      for (int k = 0; k < 20; ++k) acc += props[e * 20 + k] * Wp[k * 32 + j];
      ph[tid] = acc;
    }
    __syncthreads();
    float acc = bphys[tid];
    for (int k = 0; k < 128; ++k) acc += ph[k] * Wphys[k * 256 + tid];
    physpe[e * 256 + tid] = acc;
    return;
  }
  r -= NB_PHYS;
  if (r < NB_WP1 + NB_WP2) {  // ---- W transpose to bf16 W^T ----
    const float* W;
    unsigned short* Wt;
    int NC3, bx, by;
    if (r < NB_WP1) { W = gat1_W; Wt = wt1; NC3 = 3 * C1; bx = r % 14; by = r / 14; }
    else { int r2 = r - NB_WP1; W = gat2_W; Wt = wt2; NC3 = 3 * C2; bx = r2 % 14; by = r2 / 14; }
    int k0 = bx << 5, c0 = by << 5;
    __shared__ float ts[32][33];
    int e4 = tid << 2;
    int kk = e4 >> 5, cc = e4 & 31;
    float4 v = *(const float4*)(W + (size_t)(k0 + kk) * NC3 + c0 + cc);
    ts[kk][cc] = v.x; ts[kk][cc + 1] = v.y; ts[kk][cc + 2] = v.z; ts[kk][cc + 3] = v.w;
    __syncthreads();
    int c2 = tid & 31, kg = tid >> 5;
    ushort4 u;
    u.x = f2bf(ts[kg * 4 + 0][c2]); u.y = f2bf(ts[kg * 4 + 1][c2]);
    u.z = f2bf(ts[kg * 4 + 2][c2]); u.w = f2bf(ts[kg * 4 + 3][c2]);
    *(ushort4*)(Wt + (size_t)(c0 + c2) * 448 + k0 + (kg << 2)) = u;
    return;
  }
  r -= NB_WP1 + NB_WP2;
  if (r < 2 * NB_FOLD) {  // ---- fold a_s/a_d through W ----
    const float* W; const float* as_; const float* ad_;
    float* wsv; float* wdv; int NC3, C, kb;
    if (r < NB_FOLD) { W = gat1_W; as_ = gat1_as; ad_ = gat1_ad; wsv = wsv1; wdv = wdv1; NC3 = 3 * C1; C = C1; kb = r << 2; }
    else { int r2 = r - NB_FOLD; W = gat2_W; as_ = gat2_as; ad_ = gat2_ad; wsv = wsv2; wdv = wdv2; NC3 = 3 * C2; C = C2; kb = r2 << 2; }
    int k = kb + wv;
    for (int h = 0; h < 3; ++h) {
      float ss = 0.f, sd = 0.f;
      for (int c = lane; c < C; c += 64) {
        float wvv = W[(size_t)k * NC3 + h * C + c];
        ss += wvv * as_[h * C + c];
        sd += wvv * ad_[h * C + c];
      }
      for (int o = 32; o > 0; o >>= 1) { ss += __shfl_xor(ss, o); sd += __shfl_xor(sd, o); }
      if (lane == 0) { wsv[k * 3 + h] = ss; wdv[k * 3 + h] = sd; }
    }
    return;
  }
  r -= 2 * NB_FOLD;
  {  // ---- pad-row value after layer 2 ----
    int c = (r << 2) + wv;
    float s = 0.f;
    for (int k = lane; k < C1; k += 64) {
      const float* wr = gat2_W + (size_t)k * (3 * C2) + c;
      s += gat1_b[k] * (wr[0] + wr[C2] + wr[2 * C2]);
    }
    for (int o = 32; o > 0; o >>= 1) s += __shfl_xor(s, o);
    if (lane == 0) pad2[c] = s * (1.f / 3.f) + gat2_b[c];
  }
}

// ---------------- packed node features x0 [total32,448] bf16 + zero pads ---
__global__ __launch_bounds__(256) void k_nodep(
    const int* __restrict__ z, const int* __restrict__ off, const int* __restrict__ natoms,
    const float* __restrict__ physpe, const float* __restrict__ latx,
    const float* __restrict__ sgx, unsigned short* __restrict__ x0) {
  int b = blockIdx.x;
  int n = natoms[b], ob = off[b];
  int tid = threadIdx.x;
  __shared__ int zl[NMAX];
  for (int t = tid; t < n; t += 256) zl[t] = z[b * NMAX + t];
  __syncthreads();
  int items = n * 56;
  for (int e = tid; e < items; e += 256) {
    int t = e / 56, c8 = (e - t * 56) << 3;
    int zt = zl[t];
    float v[8];
    if (c8 < 256) {
      float4 a = *(const float4*)(physpe + zt * 256 + c8);
      float4 c = *(const float4*)(physpe + zt * 256 + c8 + 4);
      v[0] = a.x; v[1] = a.y; v[2] = a.z; v[3] = a.w;
      v[4] = c.x; v[5] = c.y; v[6] = c.z; v[7] = c.w;
    } else if (c8 < 384) {
      float4 a = *(const float4*)(latx + b * LATH + c8 - 256);
      float4 c = *(const float4*)(latx + b * LATH + c8 - 252);
      v[0] = a.x; v[1] = a.y; v[2] = a.z; v[3] = a.w;
      v[4] = c.x; v[5] = c.y; v[6] = c.z; v[7] = c.w;
    } else {
      float4 a = *(const float4*)(sgx + b * SGE + c8 - 384);
      float4 c = *(const float4*)(sgx + b * SGE + c8 - 380);
      v[0] = a.x; v[1] = a.y; v[2] = a.z; v[3] = a.w;
      v[4] = c.x; v[5] = c.y; v[6] = c.z; v[7] = c.w;
    }
    unsigned short u[8];
    #pragma unroll
    for (int i = 0; i < 8; ++i) u[i] = f2bf(v[i]);
    *(uint4*)(x0 + (size_t)(ob + t) * PIN + c8) = *(uint4*)u;
  }
  // zero pad rows [n, kext) so GEMM's XW of pad rows is defined (NaN-safe)
  int kext = ((n + 31) >> 5) << 5;
  int pitems = (kext - n) * 56;
  for (int e = tid; e < pitems; e += 256) {
    int rr = e / 56, c8 = (e - rr * 56) << 3;
    uint4 z4; z4.x = z4.y = z4.z = z4.w = 0u;
    *(uint4*)(x0 + (size_t)(ob + n + rr) * PIN + c8) = z4;
  }
}

// ---------------- asrc/adst: one WAVE per row (coalesced) ----------------
__global__ __launch_bounds__(256) void k_av2(
    const unsigned short* __restrict__ x, const float* __restrict__ wsv,
    const float* __restrict__ wdv, const int* __restrict__ off,
    const int* __restrict__ natoms, float* __restrict__ asrc,
    float* __restrict__ adst, int K) {
  __shared__ float sw[C1 * 3], dw[C1 * 3];
  int tid = threadIdx.x;
  for (int e = tid; e < K * 3; e += 256) { sw[e] = wsv[e]; dw[e] = wdv[e]; }
  __syncthreads();
  int total = off[BB - 1] + natoms[BB - 1];
  int wv = tid >> 6, lane = tid & 63;
  int nk8 = K >> 3;
  int stride = gridDim.x << 2;
  for (int row = (blockIdx.x << 2) + wv; row < total; row += stride) {
    float s0 = 0.f, s1 = 0.f, s2 = 0.f, d0 = 0.f, d1 = 0.f, d2 = 0.f;
    if (lane < nk8) {
      uint4 raw = *(const uint4*)(x + (size_t)row * K + (lane << 3));
      unsigned short us[8];
      *(uint4*)us = raw;
      #pragma unroll
      for (int u = 0; u < 8; ++u) {
        float xv = bf2f(us[u]);
        int kb = ((lane << 3) + u) * 3;
        s0 += xv * sw[kb + 0]; s1 += xv * sw[kb + 1]; s2 += xv * sw[kb + 2];
        d0 += xv * dw[kb + 0]; d1 += xv * dw[kb + 1]; d2 += xv * dw[kb + 2];
      }
    }
    #pragma unroll
    for (int o = 32; o > 0; o >>= 1) {
      s0 += __shfl_xor(s0, o); s1 += __shfl_xor(s1, o); s2 += __shfl_xor(s2, o);
      d0 += __shfl_xor(d0, o); d1 += __shfl_xor(d1, o); d2 += __shfl_xor(d2, o);
    }
    if (lane == 0) {
      asrc[row * 3 + 0] = s0; asrc[row * 3 + 1] = s1; asrc[row * 3 + 2] = s2;
      adst[row * 3 + 0] = d0; adst[row * 3 + 1] = d1; adst[row * 3 + 2] = d2;
    }
  }
}

// ---------------- alpha materialization (sharded): one (b,h,mtile)/block ---
#define MTMAX 17
__global__ __launch_bounds__(256) void k_alpha(
    const float* __restrict__ asrc, const float* __restrict__ adst,
    const int* __restrict__ off, const int* __restrict__ natoms,
    const int* __restrict__ aoff, unsigned short* __restrict__ alpha) {
  int bid = blockIdx.x;
  int b = bid & (BB - 1);
  int hm = bid >> 8;
  int h = hm % 3;
  int mt = hm / 3;
  int n = natoms[b];
  if (n == 0) return;
  int mtn = (n + 15) >> 4;
  if (mt >= mtn) return;
  int ktn = (n + 31) >> 5;
  int rext = mtn << 4, kext = ktn << 5;
  int ob = off[b];
  size_t ab = (size_t)aoff[b] + (size_t)h * rext * kext;
  int tid = threadIdx.x;
  int wv = tid >> 6, lane = tid & 63;
  __shared__ float asl[288];
  for (int j = tid; j < kext; j += 256)
    asl[j] = (j < n) ? asrc[(ob + j) * 3 + h] : 0.f;
  __syncthreads();
  #pragma unroll
  for (int r = 0; r < 4; ++r) {
    int i = (mt << 4) + (wv << 2) + r;
    unsigned short* rowp = alpha + ab + (size_t)i * kext;
    if (i >= n) {
      for (int j = lane; j < kext; j += 64) rowp[j] = 0;
      continue;
    }
    float ad = adst[(ob + i) * 3 + h];
    float m = -1e30f;
    for (int j = lane; j < n; j += 64) {
      float sc = asl[j] + ad;
      sc = fmaxf(sc, 0.2f * sc);
      m = fmaxf(m, sc);
    }
    for (int o = 32; o > 0; o >>= 1) m = fmaxf(m, __shfl_xor(m, o));
    float s = 0.f;
    for (int j = lane; j < n; j += 64) {
      float sc = asl[j] + ad;
      sc = fmaxf(sc, 0.2f * sc);
      s += __expf(sc - m);
    }
    for (int o = 32; o > 0; o >>= 1) s += __shfl_xor(s, o);
    float rs = 1.f / s;
    for (int j = lane; j < kext; j += 64) {
      float v = 0.f;
      if (j < n) {
        float sc = asl[j] + ad;
        sc = fmaxf(sc, 0.2f * sc);
        v = __expf(sc - m) * rs;
      }
      rowp[j] = f2bf(v);
    }
  }
}

// ---------------- chunked dense GEMM: xwT rows = chunk cols, transposed ----
// Templated BN = 64*NCB (R7: NCB=2 -> 16 MFMA/wave/k-step, X re-read 3x).
// BM=128 BK=32, gld16 dbuf, XOR-swizzled chunks (both-sides involution).
// Epilogue: transpose through LDS in NCB passes of 64 c-rows, coalesced
// 64-B row writes (no partial-line RMW).
template <int NCB>
__global__ __launch_bounds__(256, 4) void k_gemm(
    const unsigned short* __restrict__ X, const unsigned short* __restrict__ W,
    const int* __restrict__ meta, const float* __restrict__ zerobuf,
    unsigned short* __restrict__ xwT, int C, int cb0) {
  int total = meta[0];
  int mb = blockIdx.x / 3;
  int m0 = mb << 7;
  if (m0 >= total) return;
  int h = blockIdx.x - mb * 3;
  int colbase = h * C + (cb0 << 6);       // row base in Wt (NCB*64 rows)
  int bandbase = h * (NCB << 6);          // row base in xwT chunk
  int tid = threadIdx.x;
  int wv = tid >> 6, lane = tid & 63;
  int m16 = lane & 15, q = lane >> 4;

  // LDS: As 2x4096 shorts, Bs 2x(2048*NCB) shorts. Epilogue reuses smem as
  // a 64x132 transpose buffer per pass (8448 shorts <= 16384).
  __shared__ unsigned short smem[8192 + 4096 * NCB];
  unsigned short* As0 = smem;
  unsigned short* As1 = smem + 4096;
  unsigned short* Bs0 = smem + 8192;
  unsigned short* Bs1 = smem + 8192 + 2048 * NCB;

  int l4 = lane >> 2, ci = lane & 3;
  int ra0 = (wv << 4) + l4;
  int ra1 = ra0 + 64;
  int rb  = (wv << 4) + l4;
  // pre-swizzled global sources (LDS dest linear; read applies same XOR)
  const unsigned short* asrc0 = (m0 + ra0 < total)
      ? (X + (size_t)(m0 + ra0) * 448 + ((ci ^ (ra0 & 3)) << 3))
      : (const unsigned short*)zerobuf;
  const unsigned short* asrc1 = (m0 + ra1 < total)
      ? (X + (size_t)(m0 + ra1) * 448 + ((ci ^ (ra1 & 3)) << 3))
      : (const unsigned short*)zerobuf;
  const unsigned short* bsrc = W + (size_t)(colbase + rb) * 448 + ((ci ^ (rb & 3)) << 3);
  // rows rb+64 (NCB==2): (rb+64)&3 == rb&3 -> same swizzle, source +64*448

  floatx4 acc[2][4 * NCB];
  #pragma unroll
  for (int ti = 0; ti < 2; ++ti)
    #pragma unroll
    for (int nt = 0; nt < 4 * NCB; ++nt) acc[ti][nt] = (floatx4)0.f;

  gld16(asrc0, As0 + (wv << 9));
  gld16(asrc1, As0 + 2048 + (wv << 9));
  gld16(bsrc, Bs0 + (wv << 9));
  if constexpr (NCB == 2) gld16(bsrc + (size_t)64 * 448, Bs0 + 2048 + (wv << 9));
  __syncthreads();

  #pragma unroll 2
  for (int s = 0; s < 14; ++s) {
    int cur = s & 1;
    unsigned short* Ab = cur ? As1 : As0;
    unsigned short* Bb = cur ? Bs1 : Bs0;
    if (s < 13) {
      int k1 = (s + 1) << 5;
      unsigned short* An = cur ? As0 : As1;
      unsigned short* Bn = cur ? Bs0 : Bs1;
      gld16(asrc0 + k1, An + (wv << 9));
      gld16(asrc1 + k1, An + 2048 + (wv << 9));
      gld16(bsrc + k1, Bn + (wv << 9));
      if constexpr (NCB == 2) gld16(bsrc + (size_t)64 * 448 + k1, Bn + 2048 + (wv << 9));
    }
    shortx8 bfr[4 * NCB];
    #pragma unroll
    for (int nt = 0; nt < 4 * NCB; ++nt) {
      int rr = (nt << 4) + m16;
      bfr[nt] = *(const shortx8*)(Bb + rr * 32 + ((q ^ (rr & 3)) << 3));
    }
    #pragma unroll
    for (int ti = 0; ti < 2; ++ti) {
      int ra = ((((wv << 1) + ti) << 4) + m16);
      shortx8 a = *(const shortx8*)(Ab + ra * 32 + ((q ^ (ra & 3)) << 3));
      #pragma unroll
      for (int nt = 0; nt < 4 * NCB; ++nt)
        acc[ti][nt] = __builtin_amdgcn_mfma_f32_16x16x32_bf16(a, bfr[nt], acc[ti][nt], 0, 0, 0);
    }
    __syncthreads();
  }

  // epilogue: NCB passes of 64 c-rows through LDS, coalesced row writes
  unsigned short* tb_ = smem;  // 64 x 132 shorts per pass
  #pragma unroll
  for (int pass = 0; pass < NCB; ++pass) {
    __syncthreads();
    #pragma unroll
    for (int ti = 0; ti < 2; ++ti) {
      int j0 = (((wv << 1) + ti) << 4) + (q << 2);
      #pragma unroll
      for (int ntl = 0; ntl < 4; ++ntl) {
        int c = (ntl << 4) + m16;
        floatx4 d = acc[ti][(pass << 2) + ntl];
        ushort4 u;
        u.x = f2bf(d[0]); u.y = f2bf(d[1]); u.z = f2bf(d[2]); u.w = f2bf(d[3]);
        *(ushort4*)(tb_ + c * 132 + j0) = u;
      }
    }
    __syncthreads();
    {
      int c = tid >> 2, js = (tid & 3) << 5;
      int jglob = m0 + js;
      if (jglob < total) {  // total, js 32-aligned -> whole run valid
        unsigned short* dst = xwT + (size_t)(bandbase + (pass << 6) + c) * total + jglob;
        const unsigned short* src = tb_ + c * 132 + js;
        *(uint4*)(dst)      = *(const uint4*)(src);
        *(uint4*)(dst + 8)  = *(const uint4*)(src + 8);
        *(uint4*)(dst + 16) = *(const uint4*)(src + 16);
        *(uint4*)(dst + 24) = *(const uint4*)(src + 24);
      }
    }
  }
}

// ---------------- chunked phase B: out += mean_h(alpha_h @ XW_h) + bias ----
// R8: HAND-PIPELINED k-loop. R7's `#pragma unroll 4` was a no-op (runtime
// trip count; VGPR stayed 40 -> no extra load buffers, still ~6 loads in
// flight, 770 GB/s latency-bound). This version software-pipelines with
// NAMED register sets (rule #20: static indexing): issue iter k+1's 6
// independent loads (tb x4, af x2) into the B-set while MFMAs consume the
// A-set -> ~12 loads in flight. No LDS, no barriers.
#define NMT 3
__global__ __launch_bounds__(256, 4) void k_phaseB(
    const unsigned short* __restrict__ xwT, const unsigned short* __restrict__ alpha,
    const int* __restrict__ aoff, const int* __restrict__ off,
    const int* __restrict__ natoms, const int* __restrict__ meta,
    const float* __restrict__ bias, unsigned short* __restrict__ xout,
    int C, int cb0, int ncb) {
  int pitch = meta[0];
  int bid = blockIdx.x;
  int b = bid & (BB - 1);
  int g = bid >> 8;
  int i = g / NMT;
  int mg = g - i * NMT;
  int c0 = (cb0 + i) << 6;
  int n = natoms[b];
  if (n == 0) return;
  int mtn = (n + 15) >> 4;
  if ((mg << 3) >= mtn) return;   // whole block's mt range empty
  int ob = off[b];
  size_t ab = (size_t)aoff[b];
  int tid = threadIdx.x;
  int wv = tid >> 6, lane = tid & 63;
  int m16 = lane & 15, q = lane >> 4;
  int jmax = mtn << 4;
  int ktn = (n + 31) >> 5;
  int kext = ktn << 5;
  size_t hstride = (size_t)jmax * kext;

  int mt0 = (mg << 3) + (wv << 1);   // this wave: mt0, mt0+1 (covers 0..23)
  bool act0 = mt0 < mtn;
  bool act1 = mt0 + 1 < mtn;

  floatx4 acc[2][4];
  #pragma unroll
  for (int t_i = 0; t_i < 2; ++t_i)
    #pragma unroll
    for (int nt = 0; nt < 4; ++nt) acc[t_i][nt] = (floatx4)0.f;

  if (act0) {
    for (int h = 0; h < 3; ++h) {
      const unsigned short* ap0 = alpha + ab + (size_t)h * hstride
          + (size_t)((mt0 << 4) + m16) * kext + (q << 3);
      const unsigned short* ap1 = ap0 + (size_t)(kext << 4);  // mt0+1
      const unsigned short* xb = xwT
          + (size_t)(((h * ncb + i) << 6) + m16) * pitch + ob + (q << 3);
      const size_t xs = (size_t)pitch << 4;  // 16 rows stride

      // prologue: load iter 0 into A-set
      shortx8 tA0 = *(const shortx8*)(xb);
      shortx8 tA1 = *(const shortx8*)(xb + xs);
      shortx8 tA2 = *(const shortx8*)(xb + 2 * xs);
      shortx8 tA3 = *(const shortx8*)(xb + 3 * xs);
      shortx8 aA0 = *(const shortx8*)(ap0);
      shortx8 aA1 = act1 ? *(const shortx8*)(ap1) : (shortx8)(short)0;

      for (int k0p = 0; k0p < kext; k0p += 32) {
        int k1 = k0p + 32;
        shortx8 tB0, tB1, tB2, tB3, aB0, aB1;
        if (k1 < kext) {   // issue next iter's loads (independent addresses)
          tB0 = *(const shortx8*)(xb + k1);
          tB1 = *(const shortx8*)(xb + xs + k1);
          tB2 = *(const shortx8*)(xb + 2 * xs + k1);
          tB3 = *(const shortx8*)(xb + 3 * xs + k1);
          aB0 = *(const shortx8*)(ap0 + k1);
          aB1 = act1 ? *(const shortx8*)(ap1 + k1) : (shortx8)(short)0;
        }
        // consume A-set
        acc[0][0] = __builtin_amdgcn_mfma_f32_16x16x32_bf16(aA0, tA0, acc[0][0], 0, 0, 0);
        acc[0][1] = __builtin_amdgcn_mfma_f32_16x16x32_bf16(aA0, tA1, acc[0][1], 0, 0, 0);
        acc[0][2] = __builtin_amdgcn_mfma_f32_16x16x32_bf16(aA0, tA2, acc[0][2], 0, 0, 0);
        acc[0][3] = __builtin_amdgcn_mfma_f32_16x16x32_bf16(aA0, tA3, acc[0][3], 0, 0, 0);
        if (act1) {
          acc[1][0] = __builtin_amdgcn_mfma_f32_16x16x32_bf16(aA1, tA0, acc[1][0], 0, 0, 0);
          acc[1][1] = __builtin_amdgcn_mfma_f32_16x16x32_bf16(aA1, tA1, acc[1][1], 0, 0, 0);
          acc[1][2] = __builtin_amdgcn_mfma_f32_16x16x32_bf16(aA1, tA2, acc[1][2], 0, 0, 0);
          acc[1][3] = __builtin_amdgcn_mfma_f32_16x16x32_bf16(aA1, tA3, acc[1][3], 0, 0, 0);
        }
        if (k1 < kext) {   // rotate B -> A
          tA0 = tB0; tA1 = tB1; tA2 = tB2; tA3 = tB3;
          aA0 = aB0; aA1 = aB1;
        }
      }
    }
  }
  float bq[4];
  #pragma unroll
  for (int nt = 0; nt < 4; ++nt) bq[nt] = bias[c0 + (nt << 4) + m16];
  const float inv3 = 1.f / 3.f;
  #pragma unroll
  for (int t_i = 0; t_i < 2; ++t_i) {
    int mt = mt0 + t_i;
    if (mt < mtn) {
      #pragma unroll
      for (int nt = 0; nt < 4; ++nt) {
        floatx4 d = acc[t_i][nt];
        int cidx = c0 + (nt << 4) + m16;
        #pragma unroll
        for (int r = 0; r < 4; ++r) {
          int ii = (mt << 4) + (q << 2) + r;
          if (ii < n) xout[(size_t)(ob + ii) * C + cidx] = f2bf(d[r] * inv3 + bq[nt]);
        }
      }
    }
  }
  // zero pad rows [n, kext) of this cblk -- only the mg==0 block does it
  if (mg == 0) {
    for (int e = tid; e < ((kext - n) << 4); e += 256) {
      int row = n + (e >> 4);
      int c = c0 + ((e & 15) << 2);
      ushort4 z4; z4.x = z4.y = z4.z = z4.w = 0;
      *(ushort4*)(xout + (size_t)(ob + row) * C + c) = z4;
    }
  }
}

// ===== merged readout + head MLP: block/graph, 512 threads =================
__global__ __launch_bounds__(512) void k_feat_head(
    const unsigned short* __restrict__ x2, const float* __restrict__ pad2,
    const int* __restrict__ off, const int* __restrict__ natoms,
    const float* __restrict__ sgx, const float* __restrict__ latx,
    const float* __restrict__ W1, const float* __restrict__ b1,
    const float* __restrict__ g1, const float* __restrict__ be1,
    const float* __restrict__ m1, const float* __restrict__ v1,
    const float* __restrict__ W2, const float* __restrict__ b2,
    const float* __restrict__ g2, const float* __restrict__ be2,
    const float* __restrict__ m2, const float* __restrict__ v2,
    const float* __restrict__ W3, const float* __restrict__ b3,
    float* __restrict__ out) {
  int b = blockIdx.x, tid = threadIdx.x;  // 512
  int wv8 = tid >> 6, lane = tid & 63;
  int n = natoms[b], ob = off[b];
  __shared__ float part[8][256];
  __shared__ float f[PIN];
  __shared__ float h1[P1];
  __shared__ float h2[P1];
  __shared__ float red[512];
  float a0 = 0.f, a1 = 0.f, a2 = 0.f, a3 = 0.f;
  for (int r = wv8; r < n; r += 8) {
    uint2 raw = *(const uint2*)(x2 + (size_t)(ob + r) * C2 + (lane << 2));
    unsigned short us[4];
    *(uint2*)us = raw;
    a0 += bf2f(us[0]); a1 += bf2f(us[1]); a2 += bf2f(us[2]); a3 += bf2f(us[3]);
  }
  {
    float4 p = make_float4(a0, a1, a2, a3);
    *(float4*)&part[wv8][lane << 2] = p;
  }
  __syncthreads();
  if (tid < 256) {
    float s = 0.f;
    #pragma unroll
    for (int w = 0; w < 8; ++w) s += part[w][tid];
    f[tid] = s + (float)(NMAX - n) * pad2[tid];
  } else if (tid < 320) {
    f[tid] = sgx[b * SGE + (tid - 256)];
  } else if (tid < 448) {
    f[tid] = latx[b * LATH + (tid - 320)];
  }
  __syncthreads();
  {
    int o = tid;
    float acc = b1[o];
    for (int k = 0; k < PIN; ++k) acc += f[k] * W1[k * P1 + o];
    acc = (acc - m1[o]) * g1[o] * rsqrtf(v1[o] + EPSB) + be1[o];
    h1[o] = acc >= 0.f ? acc : 0.2f * acc;
  }
  __syncthreads();
  {
    int o = tid;
    float acc = b2[o];
    for (int k = 0; k < P1; ++k) acc += h1[k] * W2[k * P1 + o];
    acc = (acc - m2[o]) * g2[o] * rsqrtf(v2[o] + EPSB) + be2[o];
    h2[o] = acc >= 0.f ? acc : 0.2f * acc;
  }
  __syncthreads();
  red[tid] = h2[tid] * W3[tid];
  __syncthreads();
  for (int s = 256; s > 0; s >>= 1) {
    if (tid < s) red[tid] += red[tid + s];
    __syncthreads();
  }
  if (tid == 0) out[b] = red[0] + b3[0];
}

extern "C" void kernel_launch(void* const* d_in, const int* in_sizes, int n_in,
                              void* d_out, int out_size, void* d_ws, size_t ws_size,
                              hipStream_t stream) {
  const int*   comp       = (const int*)d_in[0];
  const int*   sg         = (const int*)d_in[1];
  const float* lat        = (const float*)d_in[2];
  const int*   period_idx = (const int*)d_in[3];
  const int*   group_idx  = (const int*)d_in[4];
  const float* sg_emb     = (const float*)d_in[5];
  const float* lat_W1     = (const float*)d_in[6];
  const float* lat_b1     = (const float*)d_in[7];
  const float* lat_bn1_g  = (const float*)d_in[8];
  const float* lat_bn1_b  = (const float*)d_in[9];
  const float* lat_bn1_m  = (const float*)d_in[10];
  const float* lat_bn1_v  = (const float*)d_in[11];
  const float* lat_W2     = (const float*)d_in[12];
  const float* lat_b2     = (const float*)d_in[13];
  const float* lat_bn2_g  = (const float*)d_in[14];
  const float* lat_bn2_b  = (const float*)d_in[15];
  const float* lat_bn2_m  = (const float*)d_in[16];
  const float* lat_bn2_v  = (const float*)d_in[17];
  const float* z_emb      = (const float*)d_in[18];
  const float* period_t   = (const float*)d_in[19];
  const float* group_t    = (const float*)d_in[20];
  const float* props      = (const float*)d_in[21];
  const float* W_props    = (const float*)d_in[22];
  const float* b_props    = (const float*)d_in[23];
  const float* W_phys     = (const float*)d_in[24];
  const float* b_phys     = (const float*)d_in[25];
  const float* gat1_W     = (const float*)d_in[26];
  const float* gat1_as    = (const float*)d_in[27];
  const float* gat1_ad    = (const float*)d_in[28];
  const float* gat1_b     = (const float*)d_in[29];
  const float* gat2_W     = (const float*)d_in[30];
  const float* gat2_as    = (const float*)d_in[31];
  const float* gat2_ad    = (const float*)d_in[32];
  const float* gat2_b     = (const float*)d_in[33];
  const float* pW1        = (const float*)d_in[34];
  const float* pb1        = (const float*)d_in[35];
  const float* pbn1_g     = (const float*)d_in[36];
  const float* pbn1_b     = (const float*)d_in[37];
  const float* pbn1_m     = (const float*)d_in[38];
  const float* pbn1_v     = (const float*)d_in[39];
  const float* pW2        = (const float*)d_in[40];
  const float* pb2        = (const float*)d_in[41];
  const float* pbn2_g     = (const float*)d_in[42];
  const float* pbn2_b     = (const float*)d_in[43];
  const float* pbn2_m     = (const float*)d_in[44];
  const float* pbn2_v     = (const float*)d_in[45];
  const float* pW3        = (const float*)d_in[46];
  const float* pb3        = (const float*)d_in[47];

  float* ws = (float*)d_ws;
  const size_t o_sgx  = 0;
  const size_t o_latx = o_sgx  + (size_t)BB * SGE;
  const size_t o_nat  = o_latx + (size_t)BB * LATH;
  const size_t o_off  = o_nat  + BB;
  const size_t o_aoff = o_off  + BB;
  const size_t o_meta = o_aoff + BB;
  const size_t o_z    = o_meta + 64;
  const size_t o_phys = o_z    + (size_t)BB * NMAX;
  const size_t o_wsv1 = o_phys + (size_t)NEL * 256;
  const size_t o_wdv1 = o_wsv1 + (size_t)C1 * 3;
  const size_t o_wsv2 = o_wdv1 + (size_t)C1 * 3;
  const size_t o_wdv2 = o_wsv2 + (size_t)C1 * 3;
  const size_t o_asrc = o_wdv2 + (size_t)C1 * 3;
  const size_t o_adst = o_asrc + (size_t)BB * NMAX * 3;
  const size_t o_pad2 = o_adst + (size_t)BB * NMAX * 3;
  const size_t o_zero = o_pad2 + 256;
  const size_t o_wt1  = o_zero + 256;
  const size_t o_wt2  = o_wt1  + (size_t)(3 * C1) * PIN / 2;
  const size_t o_x0   = o_wt2  + (size_t)(3 * C2) * C1 / 2;
  const size_t o_x1   = o_x0   + (size_t)XROWCAP * PIN / 2;  // 9.86M floats
  const size_t o_alph = o_x1   + (size_t)XROWCAP * PIN / 2;
  const size_t o_xwt  = o_alph + 9500000;                    // alpha ~35.4 MB actual
  // xwT chunk: 384 rows x XROWCAP shorts = 33.8 MB -> total ws ~155 MB

  float* sgx    = ws + o_sgx;
  float* latx   = ws + o_latx;
  int*   natoms = (int*)(ws + o_nat);
  int*   off    = (int*)(ws + o_off);
  int*   aoff   = (int*)(ws + o_aoff);
  int*   meta   = (int*)(ws + o_meta);
  int*   z      = (int*)(ws + o_z);
  float* physpe = ws + o_phys;
  float* wsv1   = ws + o_wsv1;
  float* wdv1   = ws + o_wdv1;
  float* wsv2   = ws + o_wsv2;
  float* wdv2   = ws + o_wdv2;
  float* asrc   = ws + o_asrc;
  float* adst   = ws + o_adst;
  float* pad2   = ws + o_pad2;
  float* zerobuf = ws + o_zero;
  unsigned short* wt1   = (unsigned short*)(ws + o_wt1);
  unsigned short* wt2   = (unsigned short*)(ws + o_wt2);
  unsigned short* x0    = (unsigned short*)(ws + o_x0);
  unsigned short* x1    = (unsigned short*)(ws + o_x1);
  unsigned short* x2    = x0;
  unsigned short* xwT   = (unsigned short*)(ws + o_xwt);
  unsigned short* alpha = (unsigned short*)(ws + o_alph);

  const int ALG = BB * 3 * MTMAX;

  k_setup<<<SETUP_GRID, 256, 0, stream>>>(
      comp, sg, lat, sg_emb,
      lat_W1, lat_b1, lat_bn1_g, lat_bn1_b, lat_bn1_m, lat_bn1_v,
      lat_W2, lat_b2, lat_bn2_g, lat_bn2_b, lat_bn2_m, lat_bn2_v,
      period_idx, group_idx, z_emb, period_t, group_t, props,
      W_props, b_props, W_phys, b_phys,
      gat1_W, gat1_as, gat1_ad, gat1_b,
      gat2_W, gat2_as, gat2_ad, gat2_b,
      sgx, latx, z, natoms, off, aoff, meta, zerobuf, physpe,
      wt1, wt2, wsv1, wdv1, wsv2, wdv2, pad2);

  k_nodep<<<BB, 256, 0, stream>>>(z, off, natoms, physpe, latx, sgx, x0);

  // ---- GAT layer 1 (C1=448 -> 7 cblks in chunks of 2,2,2,1) ----
  k_av2<<<1024, 256, 0, stream>>>(x0, wsv1, wdv1, off, natoms, asrc, adst, PIN);
  k_alpha<<<ALG, 256, 0, stream>>>(asrc, adst, off, natoms, aoff, alpha);
  {
    const int cbs[4] = {0, 2, 4, 6};
    for (int c = 0; c < 3; ++c) {
      k_gemm<2><<<GJT * 3, 256, 0, stream>>>(x0, wt1, meta, zerobuf, xwT, C1, cbs[c]);
      k_phaseB<<<2 * NMT * BB, 256, 0, stream>>>(xwT, alpha, aoff, off,
          natoms, meta, gat1_b, x1, C1, cbs[c], 2);
    }
    k_gemm<1><<<GJT * 3, 256, 0, stream>>>(x0, wt1, meta, zerobuf, xwT, C1, 6);
    k_phaseB<<<1 * NMT * BB, 256, 0, stream>>>(xwT, alpha, aoff, off,
        natoms, meta, gat1_b, x1, C1, 6, 1);
  }

  // ---- GAT layer 2 (C2=256 -> 4 cblks in chunks of 2,2) ----
  k_av2<<<1024, 256, 0, stream>>>(x1, wsv2, wdv2, off, natoms, asrc, adst, C1);
  k_alpha<<<ALG, 256, 0, stream>>>(asrc, adst, off, natoms, aoff, alpha);
  for (int c = 0; c < 2; ++c) {
    k_gemm<2><<<GJT * 3, 256, 0, stream>>>(x1, wt2, meta, zerobuf, xwT, C2, c * 2);
    k_phaseB<<<2 * NMT * BB, 256, 0, stream>>>(xwT, alpha, aoff, off, natoms,
        meta, gat2_b, x2, C2, c * 2, 2);
  }

  // ---- merged readout + head ----
  k_feat_head<<<BB, 512, 0, stream>>>(x2, pad2, off, natoms, sgx, latx,
      pW1, pb1, pbn1_g, pbn1_b, pbn1_m, pbn1_v,
      pW2, pb2, pbn2_g, pbn2_b, pbn2_m, pbn2_v,
      pW3, pb3, (float*)d_out);
}